// Round 7
// baseline (3368.451 us; speedup 1.0000x reference)
//
#include <hip/hip_runtime.h>
#include <hip/hip_bf16.h>
#include <stdint.h>

#define HID 128
#define LAYERS 5

typedef __attribute__((ext_vector_type(8))) short short8;
typedef __attribute__((ext_vector_type(4))) float f32x4;

__device__ __forceinline__ float bf2f(unsigned int u16) {
  union { unsigned int i; float f; } c; c.i = u16 << 16; return c.f;
}
__device__ __forceinline__ unsigned short f2bf(float f) {
  union { float f; unsigned int i; } c; c.f = f;
  unsigned int r = c.i + 0x7fffu + ((c.i >> 16) & 1u);
  return (unsigned short)(r >> 16);
}
__device__ __forceinline__ float fexp(float x) {
  float r; asm("v_exp_f32 %0, %1" : "=v"(r) : "v"(x * 1.44269504f)); return r;
}
__device__ __forceinline__ float frcp(float x) {
  float r; asm("v_rcp_f32 %0, %1" : "=v"(r) : "v"(x)); return r;
}
__device__ __forceinline__ float siluf(float v) { return v * frcp(1.f + fexp(-v)); }

// ---------------- bf16 MFMA GEMM: C[M, NCT*16] = A[M, KS*32] @ Bt^T + bias ---------------
template<int KS, int NCT, bool BF16OUT>
__launch_bounds__(256)
__global__ void gemm_bf16_kernel(const unsigned short* __restrict__ A,
                                 const unsigned short* __restrict__ Bt,
                                 const float* __restrict__ bias,
                                 void* __restrict__ Cv, int M) {
  constexpr int K = KS * 32;
  constexpr int SLOTS = KS * 4;
  constexpr int SSTR = (SLOTS + 7) & ~7;
  __shared__ unsigned short wlds[NCT * 16 * SSTR * 8];
  for (int i = threadIdx.x; i < NCT * 16 * SLOTS; i += 256) {
    int col = i / SLOTS, slot = i % SLOTS;
    int phys = slot ^ (col & 7);
    *(uint4*)&wlds[(col * SSTR + phys) * 8] = *(const uint4*)(Bt + (size_t)col * K + slot * 8);
  }
  __syncthreads();
  int lane = threadIdx.x & 63, wid = threadIdx.x >> 6;
  int l15 = lane & 15, l4 = lane >> 4;
  int n0 = blockIdx.x * 64 + wid * 16;
  f32x4 acc[NCT];
  #pragma unroll
  for (int ct = 0; ct < NCT; ++ct) { f32x4 z = {0.f, 0.f, 0.f, 0.f}; acc[ct] = z; }
  int ar = n0 + l15; if (ar >= M) ar = M - 1;
  #pragma unroll
  for (int kk = 0; kk < KS; ++kk) {
    short8 af = *(const short8*)(A + (size_t)ar * K + kk * 32 + l4 * 8);
    #pragma unroll
    for (int ct = 0; ct < NCT; ++ct) {
      int col = ct * 16 + l15;
      int phys = (kk * 4 + l4) ^ (col & 7);
      short8 bfr = *(const short8*)&wlds[(col * SSTR + phys) * 8];
      acc[ct] = __builtin_amdgcn_mfma_f32_16x16x32_bf16(af, bfr, acc[ct], 0, 0, 0);
    }
  }
  #pragma unroll
  for (int ct = 0; ct < NCT; ++ct) {
    int col = ct * 16 + l15;
    #pragma unroll
    for (int j = 0; j < 4; ++j) {
      int n = n0 + l4 * 4 + j;
      if (n < M) {
        float v = acc[ct][j] + bias[col];
        if (BF16OUT) ((unsigned short*)Cv)[(size_t)n * (NCT * 16) + col] = f2bf(v);
        else         ((float*)Cv)[(size_t)n * (NCT * 16) + col] = v;
      }
    }
  }
}

// ---------------- embed input/weight casts (pad K to 224) --------------------------------
__global__ void cast_atom_kernel(const float* __restrict__ atom, unsigned short* __restrict__ ab,
                                 int N, int AIN) {
  int n = blockIdx.x, k = threadIdx.x;
  if (n < N && k < 224)
    ab[(size_t)n * 224 + k] = f2bf(k < AIN ? atom[(size_t)n * AIN + k] : 0.f);
}
__global__ void prep_we_kernel(const float* __restrict__ W, unsigned short* __restrict__ Bt,
                               int AIN) {
  int i = blockIdx.x * 256 + threadIdx.x;
  if (i >= 128 * 224) return;
  int col = i / 224, k = i % 224;
  Bt[i] = f2bf(k < AIN ? W[(size_t)k * 128 + col] : 0.f);
}

// ---------------- per-feature sum/sumsq over rows (f32 input) ----------------------------
__global__ void colstats_kernel(const float* __restrict__ in, int M, float* __restrict__ stats) {
  int f = threadIdx.x & 127;
  int rl = threadIdx.x >> 7;
  float s = 0, s2 = 0;
  for (int r = blockIdx.x * 2 + rl; r < M; r += gridDim.x * 2) {
    float v = in[(size_t)r * 128 + f];
    s += v; s2 += v * v;
  }
  __shared__ float l1[256], l2[256];
  l1[threadIdx.x] = s; l2[threadIdx.x] = s2;
  __syncthreads();
  if (rl == 0) {
    atomicAdd(&stats[f],       s  + l1[128 + f]);
    atomicAdd(&stats[128 + f], s2 + l2[128 + f]);
  }
}

// ---------------- BN (+silu / +residual), writes f32 x and bf16 xb -----------------------
template<bool SILU, bool RES>
__global__ void bn_act_kernel(const float* __restrict__ in, const float* __restrict__ stats,
                              const float* __restrict__ g, const float* __restrict__ be,
                              const float* __restrict__ resid, float invM,
                              float* __restrict__ xout, unsigned short* __restrict__ xbout,
                              size_t total) {
  int f = threadIdx.x & 127;
  float mean = stats[f] * invM;
  float var  = stats[128 + f] * invM - mean * mean;
  float sc = g[f] * rsqrtf(var + 1e-5f);
  float sh = be[f] - mean * sc;
  for (size_t i = (size_t)blockIdx.x * blockDim.x + threadIdx.x; i < total;
       i += (size_t)gridDim.x * blockDim.x) {
    float v = in[i] * sc + sh;
    if (SILU) v = siluf(v);
    if (RES)  v += resid[i];
    xout[i] = v;
    xbout[i] = f2bf(v);
  }
}

// ---------------- CSR build: histogram, scan, scatter ------------------------------------
__global__ void hist_kernel(const int* __restrict__ ids, int* __restrict__ deg, int E) {
  for (int e = blockIdx.x * blockDim.x + threadIdx.x; e < E; e += gridDim.x * blockDim.x)
    atomicAdd(&deg[ids[e]], 1);
}

__global__ void scan_block_kernel(const int* __restrict__ in, int n,
                                  int* __restrict__ excl, int* __restrict__ totals) {
  __shared__ int tmp[256];
  int idx = blockIdx.x * 256 + threadIdx.x;
  int v = (idx < n) ? in[idx] : 0;
  tmp[threadIdx.x] = v;
  __syncthreads();
  for (int o = 1; o < 256; o <<= 1) {
    int t = (threadIdx.x >= o) ? tmp[threadIdx.x - o] : 0;
    __syncthreads();
    tmp[threadIdx.x] += t;
    __syncthreads();
  }
  if (idx < n) excl[idx] = tmp[threadIdx.x] - v;
  if (threadIdx.x == 255 && totals) totals[blockIdx.x] = tmp[255];
}

__global__ void scan_add_kernel(const int* __restrict__ excl, const int* __restrict__ tot_excl,
                                const int* __restrict__ indeg, int* __restrict__ cstart, int n) {
  int idx = blockIdx.x * 256 + threadIdx.x;
  if (idx < n) {
    int v = excl[idx] + tot_excl[blockIdx.x];
    cstart[idx] = v;
    if (idx == n - 1) cstart[n] = v + indeg[idx];
  }
}

__global__ void scatter_kernel(const int* __restrict__ src, const int* __restrict__ dst,
                               const int* __restrict__ cstart, int* __restrict__ fill,
                               int* __restrict__ csrc, int* __restrict__ cdst, int E) {
  for (int e = blockIdx.x * blockDim.x + threadIdx.x; e < E; e += gridDim.x * blockDim.x) {
    int d = dst[e];
    int pos = cstart[d] + atomicAdd(&fill[d], 1);
    csrc[pos] = src[e];
    cdst[pos] = d;
  }
}

// ---------------- weight preps (bf16, [col][k] layout) -----------------------------------
__global__ void prep_wg_kernel(const float* __restrict__ WgL, const float* __restrict__ bgL,
                               unsigned short* __restrict__ Bt, float* __restrict__ bias) {
  int i = blockIdx.x * 256 + threadIdx.x;
  if (i < 256 * 128) {
    int col = i >> 7, k = i & 127;
    int c = col & 127, h = c >> 5, d = c & 31;
    int krow = (col < 128) ? k : 128 + k;
    Bt[i] = f2bf(WgL[((size_t)h * 256 + krow) * 32 + d]);
  }
  if (i < 256) bias[i] = (i < 128) ? 0.f : bgL[i - 128];
}

__global__ void prep_mv_kernel(const float* __restrict__ Wm, const float* __restrict__ Wv,
                               const float* __restrict__ bm, const float* __restrict__ bv,
                               unsigned short* __restrict__ Bt, float* __restrict__ bias) {
  int i = blockIdx.x * 256 + threadIdx.x;
  if (i < 256 * 128) {
    int col = i >> 7, k = i & 127;
    Bt[i] = f2bf(col < 128 ? Wm[(size_t)k * 128 + col] : Wv[(size_t)k * 128 + col - 128]);
  }
  if (i < 256) bias[i] = (i < 128) ? bm[i] : bv[i - 128];
}

// ---------------- pq (bf16 input) + gate-BN node-stat accumulation -----------------------
// p = x.Wf_src ; q = x.Wf_dst + bf ; gstats[0] += od*p+id*q ; gstats[1] += od*p^2+id*q^2
__global__ void pq_kernel(const unsigned short* __restrict__ xb, const float* __restrict__ WfL,
                          const float* __restrict__ bfL, const int* __restrict__ indeg,
                          const int* __restrict__ outdeg, float* __restrict__ p,
                          float* __restrict__ q, float* __restrict__ gstats, int N) {
  __shared__ float wf[256];
  wf[threadIdx.x] = WfL[threadIdx.x];
  __syncthreads();
  int wid = threadIdx.x >> 6, lane = threadIdx.x & 63;
  int f0 = lane * 2;
  float bf0 = bfL[0];
  float t1 = 0, t2 = 0;
  for (int n = blockIdx.x * 4 + wid; n < N; n += gridDim.x * 4) {
    unsigned xv = *(const unsigned*)(xb + ((size_t)n << 7) + f0);
    float x0 = bf2f(xv & 0xffffu), x1 = bf2f(xv >> 16);
    float pp = x0 * wf[f0]       + x1 * wf[f0 + 1];
    float qq = x0 * wf[128 + f0] + x1 * wf[129 + f0];
    #pragma unroll
    for (int o = 32; o; o >>= 1) { pp += __shfl_down(pp, o); qq += __shfl_down(qq, o); }
    if (lane == 0) {
      qq += bf0;
      p[n] = pp; q[n] = qq;
      float od = (float)outdeg[n], id = (float)indeg[n];
      t1 += od * pp + id * qq;
      t2 += od * pp * pp + id * qq * qq;
    }
  }
  if (lane == 0) {
    atomicAdd(&gstats[0], t1);
    atomicAdd(&gstats[1], t2);
  }
}

// ---------------- z-stats node-factorable part -------------------------------------------
__global__ void zstat_node_kernel(const unsigned short* __restrict__ UVb,
                                  const int* __restrict__ indeg, const int* __restrict__ outdeg,
                                  float* __restrict__ zstats, int N) {
  int lane = threadIdx.x & 63, g = threadIdx.x >> 6;
  int f0 = lane * 2, f1 = f0 + 1;
  float zs0 = 0, zq0 = 0, zs1 = 0, zq1 = 0;
  for (int n = blockIdx.x * 4 + g; n < N; n += gridDim.x * 4) {
    float od = (float)outdeg[n], id = (float)indeg[n];
    unsigned up = *(const unsigned*)(UVb + ((size_t)n << 8) + f0);
    unsigned vp = *(const unsigned*)(UVb + ((size_t)n << 8) + 128 + f0);
    float u0 = bf2f(up & 0xffffu), u1 = bf2f(up >> 16);
    float v0 = bf2f(vp & 0xffffu), v1 = bf2f(vp >> 16);
    zs0 += od * u0 + id * v0;  zq0 += od * u0 * u0 + id * v0 * v0;
    zs1 += od * u1 + id * v1;  zq1 += od * u1 * u1 + id * v1 * v1;
  }
  __shared__ float r1[4][128], r2[4][128];
  r1[g][f0] = zs0; r1[g][f1] = zs1;
  r2[g][f0] = zq0; r2[g][f1] = zq1;
  __syncthreads();
  if (threadIdx.x < 128) {
    int f = threadIdx.x;
    atomicAdd(&zstats[f],       r1[0][f] + r1[1][f] + r1[2][f] + r1[3][f]);
    atomicAdd(&zstats[128 + f], r2[0][f] + r2[1][f] + r2[2][f] + r2[3][f]);
  }
}

// ---------------- cross walk: z-cross per feature + gate cross scalar --------------------
// zc[f] += sum_e U[src,f]*V[dst,f]  (32-slot partials); gstats[2] += sum_e p[src]*q[dst]
__global__ void xwalk_kernel(const unsigned short* __restrict__ UVb,
                             const int* __restrict__ csrc, const int* __restrict__ cdst,
                             const float* __restrict__ p, const float* __restrict__ q,
                             float* __restrict__ zc_parts, float* __restrict__ gstats, int E) {
  int lane = threadIdx.x & 63;
  int gw = (blockIdx.x * 256 + threadIdx.x) >> 6;
  int nw = (gridDim.x * 256) >> 6;
  int f0 = lane * 2;
  float cr0 = 0, cr1 = 0, gc = 0;
  int nch = (E + 63) >> 6;
  for (int c = gw; c < nch; c += nw) {
    int e0 = c << 6, len = min(64, E - e0);
    int ee = e0 + (lane < len ? lane : len - 1);
    int idxs = csrc[ee], idxd = cdst[ee];
    if (lane < len) gc += p[idxs] * q[idxd];     // gate cross, lane-parallel
    int dcur = __shfl(idxd, 0);
    float su0 = 0, su1 = 0;
    const unsigned short* base = UVb;
    #define LDU(i) (*(const unsigned*)(base + ((size_t)__shfl(idxs, (i) < len ? (i) : len - 1) << 8) + f0))
    unsigned a0 = LDU(0), a1 = LDU(1), a2 = LDU(2), a3 = LDU(3);
    for (int bs = 0; bs < len; bs += 4) {
      unsigned b0 = LDU(bs + 4), b1 = LDU(bs + 5), b2 = LDU(bs + 6), b3 = LDU(bs + 7);
      #define PROCX(i, up) if ((i) < len) {                                        \
        int d = __shfl(idxd, (i));                                                 \
        if (d != dcur) {                                                           \
          unsigned vp = *(const unsigned*)(base + ((size_t)dcur << 8) + 128 + f0); \
          cr0 += bf2f(vp & 0xffffu) * su0; cr1 += bf2f(vp >> 16) * su1;            \
          su0 = su1 = 0; dcur = d;                                                 \
        }                                                                          \
        su0 += bf2f((up) & 0xffffu); su1 += bf2f((up) >> 16); }
      PROCX(bs + 0, a0); PROCX(bs + 1, a1); PROCX(bs + 2, a2); PROCX(bs + 3, a3);
      a0 = b0; a1 = b1; a2 = b2; a3 = b3;
    }
    unsigned vp = *(const unsigned*)(base + ((size_t)dcur << 8) + 128 + f0);
    cr0 += bf2f(vp & 0xffffu) * su0; cr1 += bf2f(vp >> 16) * su1;
    #undef PROCX
    #undef LDU
  }
  atomicAdd(&zc_parts[(blockIdx.x & 31) * 128 + f0],     cr0);
  atomicAdd(&zc_parts[(blockIdx.x & 31) * 128 + f0 + 1], cr1);
  #pragma unroll
  for (int o = 32; o; o >>= 1) gc += __shfl_down(gc, o);
  if (lane == 0) atomicAdd(&gstats[2], gc);
}

// ---------------- gate apply: edge-parallel, per-lane sum_w atomics ----------------------
__global__ void gate_wexp_kernel(const int* __restrict__ csrc, const int* __restrict__ cdst,
                                 const float* __restrict__ p, const float* __restrict__ q,
                                 const float* __restrict__ nodew, const float* __restrict__ gstats,
                                 const float* __restrict__ gfL, const float* __restrict__ befL,
                                 float* __restrict__ wexp, float* __restrict__ sum_w,
                                 int E, float invE) {
  float gm  = gstats[0] * invE;
  float gv  = (gstats[1] + 2.f * gstats[2]) * invE - gm * gm;
  float gsc = gfL[0] * rsqrtf(gv + 1e-5f);
  float gsh = befL[0] - gm * gsc;
  for (int e = blockIdx.x * blockDim.x + threadIdx.x; e < E; e += gridDim.x * blockDim.x) {
    int s = csrc[e], d = cdst[e];
    float v = (p[s] + q[d]) * gsc + gsh;
    v = v * frcp(1.f + fexp(-v));
    float we = nodew[s] * fexp(v);
    wexp[e] = we;
    atomicAdd(&sum_w[d], we);
  }
}

// ---------------- aggregate: edge-parallel, 4-deep prefetch, register segments -----------
__global__ void walk2_kernel(const unsigned short* __restrict__ UVb,
                             const int* __restrict__ csrc, const int* __restrict__ cdst,
                             const float* __restrict__ wexp, const float* __restrict__ sum_w,
                             const float* __restrict__ zstats, const float* __restrict__ zc_parts,
                             const float* __restrict__ gg, const float* __restrict__ beg,
                             float* __restrict__ h, int E, float invE) {
  int lane = threadIdx.x & 63;
  int gw = (blockIdx.x * 256 + threadIdx.x) >> 6;
  int nw = (gridDim.x * 256) >> 6;
  int f0 = lane * 2, f1 = f0 + 1;
  float cr0 = 0, cr1 = 0;
  #pragma unroll
  for (int i2 = 0; i2 < 32; ++i2) { cr0 += zc_parts[i2 * 128 + f0]; cr1 += zc_parts[i2 * 128 + f1]; }
  float zm0 = zstats[f0] * invE;
  float zv0 = (zstats[128 + f0] + 2.f * cr0) * invE - zm0 * zm0;
  float sc0 = gg[f0] * rsqrtf(zv0 + 1e-5f), sh0 = beg[f0] - zm0 * sc0;
  float zm1 = zstats[f1] * invE;
  float zv1 = (zstats[128 + f1] + 2.f * cr1) * invE - zm1 * zm1;
  float sc1 = gg[f1] * rsqrtf(zv1 + 1e-5f), sh1 = beg[f1] - zm1 * sc1;

  int nch = (E + 63) >> 6;
  for (int c = gw; c < nch; c += nw) {
    int e0 = c << 6, len = min(64, E - e0);
    int ee = e0 + (lane < len ? lane : len - 1);
    int idxs = csrc[ee], idxd = cdst[ee];
    float wv = wexp[ee];
    int dcur = __shfl(idxd, 0);
    float inv = frcp(sum_w[dcur]);
    float c0, c1;
    { unsigned vp = *(const unsigned*)(UVb + ((size_t)dcur << 8) + 128 + f0);
      c0 = bf2f(vp & 0xffffu) * sc0 + sh0; c1 = bf2f(vp >> 16) * sc1 + sh1; }
    float h0 = 0, h1 = 0;
    #define LDU(i) (*(const unsigned*)(UVb + ((size_t)__shfl(idxs, (i) < len ? (i) : len - 1) << 8) + f0))
    unsigned a0 = LDU(0), a1 = LDU(1), a2 = LDU(2), a3 = LDU(3);
    for (int bs = 0; bs < len; bs += 4) {
      unsigned b0 = LDU(bs + 4), b1 = LDU(bs + 5), b2 = LDU(bs + 6), b3 = LDU(bs + 7);
      #define PROCW(i, up) if ((i) < len) {                                          \
        int d = __shfl(idxd, (i));                                                   \
        float a = __shfl(wv, (i));                                                   \
        if (d != dcur) {                                                             \
          atomicAdd(&h[((size_t)dcur << 7) + f0], h0 * inv);                         \
          atomicAdd(&h[((size_t)dcur << 7) + f1], h1 * inv);                         \
          h0 = h1 = 0; dcur = d; inv = frcp(sum_w[d]);                               \
          unsigned vp = *(const unsigned*)(UVb + ((size_t)d << 8) + 128 + f0);       \
          c0 = bf2f(vp & 0xffffu) * sc0 + sh0; c1 = bf2f(vp >> 16) * sc1 + sh1;      \
        }                                                                            \
        float v0 = bf2f((up) & 0xffffu) * sc0 + c0;                                  \
        float v1 = bf2f((up) >> 16)     * sc1 + c1;                                  \
        v0 = v0 * frcp(1.f + fexp(-v0));                                             \
        v1 = v1 * frcp(1.f + fexp(-v1));                                             \
        h0 += a * v0; h1 += a * v1; }
      PROCW(bs + 0, a0); PROCW(bs + 1, a1); PROCW(bs + 2, a2); PROCW(bs + 3, a3);
      a0 = b0; a1 = b1; a2 = b2; a3 = b3;
    }
    atomicAdd(&h[((size_t)dcur << 7) + f0], h0 * inv);
    atomicAdd(&h[((size_t)dcur << 7) + f1], h1 * inv);
    #undef PROCW
    #undef LDU
  }
}

// ---------------- reparameterize (bf16 muv=[mu|lv] packed [N,256]) + kld -----------------
__global__ void reparam_kernel(const unsigned short* __restrict__ muv,
                               const float* __restrict__ eps,
                               float* __restrict__ x, unsigned short* __restrict__ xb,
                               float* __restrict__ kacc, size_t total) {
  float part = 0;
  for (size_t i = (size_t)blockIdx.x * blockDim.x + threadIdx.x; i < total;
       i += (size_t)gridDim.x * blockDim.x) {
    size_t n = i >> 7; int f = (int)(i & 127);
    float m = bf2f(muv[(n << 8) + f]);
    float l = bf2f(muv[(n << 8) + 128 + f]);
    float el = fexp(l);
    float v = eps[i] * fexp(0.5f * l) + m;
    x[i] = v;
    xb[i] = f2bf(v);
    part += 1.f + l - m * m - el;
  }
  #pragma unroll
  for (int o = 32; o; o >>= 1) part += __shfl_down(part, o);
  __shared__ float la[4];
  int lane = threadIdx.x & 63, wid = threadIdx.x >> 6;
  if (lane == 0) la[wid] = part;
  __syncthreads();
  if (threadIdx.x == 0) atomicAdd(kacc, la[0] + la[1] + la[2] + la[3]);
}

// ---------------- pooling: sorted gid -> run-length segmented wave sum -------------------
__global__ void pool_kernel(const float* __restrict__ x, const int* __restrict__ gid,
                            float* __restrict__ pools, float* __restrict__ cnt, int N) {
  int lane = threadIdx.x & 63;
  int gw = (blockIdx.x * 256 + threadIdx.x) >> 6;
  int nw = (gridDim.x * 256) >> 6;
  int f0 = lane * 2, f1 = f0 + 1;
  const int CH = 64;
  int nch = (N + CH - 1) / CH;
  for (int c = gw; c < nch; c += nw) {
    int n0 = c * CH, n1 = min(N, n0 + CH);
    int gcur = gid[n0];
    float a0 = 0, a1 = 0, count = 0;
    for (int n = n0; n < n1; ++n) {
      int g = gid[n];
      if (g != gcur) {
        atomicAdd(&pools[((size_t)gcur << 7) + f0], a0);
        atomicAdd(&pools[((size_t)gcur << 7) + f1], a1);
        if (lane == 0) atomicAdd(&cnt[gcur], count);
        a0 = a1 = 0; count = 0; gcur = g;
      }
      float2 xv = *(const float2*)(x + ((size_t)n << 7) + f0);
      a0 += xv.x; a1 += xv.y; count += 1.f;
    }
    atomicAdd(&pools[((size_t)gcur << 7) + f0], a0);
    atomicAdd(&pools[((size_t)gcur << 7) + f1], a1);
    if (lane == 0) atomicAdd(&cnt[gcur], count);
  }
}

__global__ void finalize_kernel(const float* __restrict__ pools, const float* __restrict__ cnt,
                                const float* __restrict__ kacc, float* __restrict__ out,
                                int NG, float invN) {
  int i = blockIdx.x * blockDim.x + threadIdx.x;
  if (i < NG * 128) {
    float c = cnt[i >> 7];
    c = c > 1.f ? c : 1.f;
    out[i] = pools[i] / c;
  }
  if (i == 0) out[NG * 128] = -0.5f * kacc[0] * invN;
}

// =========================================================================================
extern "C" void kernel_launch(void* const* d_in, const int* in_sizes, int n_in,
                              void* d_out, int out_size, void* d_ws, size_t ws_size,
                              hipStream_t stream) {
  const float* atom    = (const float*)d_in[0];
  const float* nodew   = (const float*)d_in[1];
  const float* epsp    = (const float*)d_in[2];
  const int*   src     = (const int*)d_in[3];
  const int*   dst     = (const int*)d_in[4];
  const int*   gid     = (const int*)d_in[5];
  const float* W_embed = (const float*)d_in[6];
  const float* b_embed = (const float*)d_in[7];
  const float* g_embed = (const float*)d_in[8];
  const float* be_embed= (const float*)d_in[9];
  const float* Wf      = (const float*)d_in[10];
  const float* bfp     = (const float*)d_in[11];
  const float* gfp     = (const float*)d_in[12];
  const float* befp    = (const float*)d_in[13];
  const float* Wg      = (const float*)d_in[14];
  const float* bg      = (const float*)d_in[15];
  const float* gg      = (const float*)d_in[16];
  const float* beg     = (const float*)d_in[17];
  const float* gn      = (const float*)d_in[18];
  const float* ben     = (const float*)d_in[19];
  const float* W_mu    = (const float*)d_in[20];
  const float* b_mu    = (const float*)d_in[21];
  const float* W_var   = (const float*)d_in[22];
  const float* b_var   = (const float*)d_in[23];

  const int N   = in_sizes[1];
  const int E   = in_sizes[3];
  const int AIN = in_sizes[0] / N;
  const int NG  = (out_size - 1) / HID;

  char* w = (char*)d_ws;
  size_t off = 0;
  auto alloc = [&](size_t bytes) { size_t r = off; off = (off + bytes + 255) & ~(size_t)255; return r; };
  size_t o_x    = alloc((size_t)N*HID*4);
  size_t o_xb   = alloc((size_t)N*HID*2);
  size_t o_uvb  = alloc((size_t)N*256*2);
  size_t o_h    = alloc((size_t)N*HID*4);
  size_t o_ab   = alloc((size_t)N*224*2);
  size_t o_p    = alloc((size_t)N*4);
  size_t o_q    = alloc((size_t)N*4);
  size_t o_sw   = alloc((size_t)N*4);
  size_t o_wexp = alloc((size_t)E*4);
  size_t o_csrc = alloc((size_t)E*4);
  size_t o_cdst = alloc((size_t)E*4);
  size_t o_cs   = alloc((size_t)(N+1)*4);
  size_t o_deg  = alloc((size_t)3*N*4);      // indeg | fill | outdeg
  size_t o_excl = alloc((size_t)N*4);
  size_t o_tot  = alloc(512*4);
  size_t o_bt   = alloc((size_t)256*128*2);
  size_t o_bias = alloc(256*4);
  // stats layout: [0:4) gate {sum, node-sq, cross, pad}; [4:260) z; [260:516) node; [516:516+4096) zc_parts
  size_t o_st   = alloc((516 + 32*128)*4);
  size_t o_kp   = alloc((size_t)(64 + NG*HID + NG)*4);

  float* x              = (float*)(w + o_x);
  unsigned short* xb    = (unsigned short*)(w + o_xb);
  unsigned short* UVb   = (unsigned short*)(w + o_uvb);
  float* h              = (float*)(w + o_h);
  unsigned short* atomb = (unsigned short*)(w + o_ab);
  float* p              = (float*)(w + o_p);
  float* q              = (float*)(w + o_q);
  float* sum_w          = (float*)(w + o_sw);
  float* wexp           = (float*)(w + o_wexp);
  int*   csrc           = (int*)(w + o_csrc);
  int*   cdst           = (int*)(w + o_cdst);
  int*   cstart         = (int*)(w + o_cs);
  int*   indeg          = (int*)(w + o_deg);
  int*   fill           = indeg + N;
  int*   outdeg         = indeg + 2*N;
  int*   excl           = (int*)(w + o_excl);
  int*   totals         = (int*)(w + o_tot);
  int*   tot_excl       = totals + 256;
  unsigned short* Bt    = (unsigned short*)(w + o_bt);
  float* bias           = (float*)(w + o_bias);
  float* stats          = (float*)(w + o_st);
  float* gstats         = stats;
  float* zstats         = stats + 4;
  float* nstats         = stats + 260;
  float* zc_parts       = stats + 516;
  float* kacc           = (float*)(w + o_kp);
  float* pools          = kacc + 64;
  float* cnt            = pools + (size_t)NG*HID;

  const dim3 B(256);
  const int mblk = (N + 63) / 64;
  const int nb1  = (N + 255) / 256;
  const float invN = 1.f / (float)N;
  const float invE = 1.f / (float)E;
  const size_t totalNH = (size_t)N * HID;
  const size_t st_bytes = (516 + 32*128) * 4;

  // ---- zero accumulators ----
  hipMemsetAsync(w + o_st, 0, st_bytes, stream);
  hipMemsetAsync(w + o_kp, 0, (64 + (size_t)NG*HID + NG)*4, stream);
  hipMemsetAsync(w + o_deg, 0, (size_t)3*N*4, stream);

  // ---- CSR build (dst-sorted) + degrees ----
  hist_kernel<<<dim3(1024), B, 0, stream>>>(dst, indeg, E);
  hist_kernel<<<dim3(1024), B, 0, stream>>>(src, outdeg, E);
  scan_block_kernel<<<dim3(nb1), B, 0, stream>>>(indeg, N, excl, totals);
  scan_block_kernel<<<dim3(1), B, 0, stream>>>(totals, nb1, tot_excl, nullptr);
  scan_add_kernel<<<dim3(nb1), B, 0, stream>>>(excl, tot_excl, indeg, cstart, N);
  scatter_kernel<<<dim3(1024), B, 0, stream>>>(src, dst, cstart, fill, csrc, cdst, E);

  // ---- atom embedding ----
  cast_atom_kernel<<<dim3(N), B, 0, stream>>>(atom, atomb, N, AIN);
  prep_we_kernel<<<dim3(112), B, 0, stream>>>(W_embed, Bt, AIN);
  gemm_bf16_kernel<7, 8, false><<<dim3(mblk), B, 0, stream>>>(atomb, Bt, b_embed, h, N);
  colstats_kernel<<<dim3(512), B, 0, stream>>>(h, N, nstats);
  bn_act_kernel<true,false><<<dim3(2048), B, 0, stream>>>(h, nstats, g_embed, be_embed,
                                                          x, invN, x, xb, totalNH);

  for (int l = 0; l < LAYERS; ++l) {
    if (l == 1) {
      prep_mv_kernel<<<dim3(128), B, 0, stream>>>(W_mu, W_var, b_mu, b_var, Bt, bias);
      gemm_bf16_kernel<4, 16, true><<<dim3(mblk), B, 0, stream>>>(xb, Bt, bias, UVb, N);
      reparam_kernel<<<dim3(2048), B, 0, stream>>>(UVb, epsp, x, xb, kacc, totalNH);
    }
    prep_wg_kernel<<<dim3(128), B, 0, stream>>>(Wg + (size_t)l*4*256*32, bg + l*128, Bt, bias);
    hipMemsetAsync(w + o_st, 0, st_bytes, stream);
    hipMemsetAsync(w + o_h, 0, (size_t)N*HID*4, stream);
    hipMemsetAsync(w + o_sw, 0, (size_t)N*4, stream);
    gemm_bf16_kernel<4, 16, true><<<dim3(mblk), B, 0, stream>>>(xb, Bt, bias, UVb, N);
    pq_kernel<<<dim3(2048), B, 0, stream>>>(xb, Wf + l*256, bfp + l, indeg, outdeg,
                                            p, q, gstats, N);
    xwalk_kernel<<<dim3(2048), B, 0, stream>>>(UVb, csrc, cdst, p, q, zc_parts, gstats, E);
    zstat_node_kernel<<<dim3(512), B, 0, stream>>>(UVb, indeg, outdeg, zstats, N);
    gate_wexp_kernel<<<dim3(1024), B, 0, stream>>>(csrc, cdst, p, q, nodew, gstats,
                                                   gfp + l, befp + l, wexp, sum_w, E, invE);
    walk2_kernel<<<dim3(2048), B, 0, stream>>>(UVb, csrc, cdst, wexp, sum_w, zstats, zc_parts,
                                               gg + l*128, beg + l*128, h, E, invE);
    colstats_kernel<<<dim3(512), B, 0, stream>>>(h, N, nstats);
    bn_act_kernel<false,true><<<dim3(2048), B, 0, stream>>>(h, nstats, gn + l*128, ben + l*128,
                                                            x, invN, x, xb, totalNH);
  }

  // ---- pooling + output ----
  pool_kernel<<<dim3(256), B, 0, stream>>>(x, gid, pools, cnt, N);
  finalize_kernel<<<dim3((NG*HID + 255)/256), B, 0, stream>>>(pools, cnt, kacc,
                                                              (float*)d_out, NG, invN);
}

// Round 8
// 2030.671 us; speedup vs baseline: 1.6588x; 1.6588x over previous
//
#include <hip/hip_runtime.h>
#include <hip/hip_bf16.h>
#include <stdint.h>

#define HID 128
#define LAYERS 5

typedef __attribute__((ext_vector_type(8))) short short8;
typedef __attribute__((ext_vector_type(4))) float f32x4;

__device__ __forceinline__ float bf2f(unsigned int u16) {
  union { unsigned int i; float f; } c; c.i = u16 << 16; return c.f;
}
__device__ __forceinline__ unsigned short f2bf(float f) {
  union { float f; unsigned int i; } c; c.f = f;
  unsigned int r = c.i + 0x7fffu + ((c.i >> 16) & 1u);
  return (unsigned short)(r >> 16);
}
__device__ __forceinline__ float fexp(float x) {
  float r; asm("v_exp_f32 %0, %1" : "=v"(r) : "v"(x * 1.44269504f)); return r;
}
__device__ __forceinline__ float frcp(float x) {
  float r; asm("v_rcp_f32 %0, %1" : "=v"(r) : "v"(x)); return r;
}
__device__ __forceinline__ float siluf(float v) { return v * frcp(1.f + fexp(-v)); }

// ---------------- bf16 MFMA GEMM: C[M, NCT*16] = A[M, KS*32] @ Bt^T + bias ---------------
template<int KS, int NCT, bool BF16OUT>
__launch_bounds__(256)
__global__ void gemm_bf16_kernel(const unsigned short* __restrict__ A,
                                 const unsigned short* __restrict__ Bt,
                                 const float* __restrict__ bias,
                                 void* __restrict__ Cv, int M) {
  constexpr int K = KS * 32;
  constexpr int SLOTS = KS * 4;
  constexpr int SSTR = (SLOTS + 7) & ~7;
  __shared__ unsigned short wlds[NCT * 16 * SSTR * 8];
  for (int i = threadIdx.x; i < NCT * 16 * SLOTS; i += 256) {
    int col = i / SLOTS, slot = i % SLOTS;
    int phys = slot ^ (col & 7);
    *(uint4*)&wlds[(col * SSTR + phys) * 8] = *(const uint4*)(Bt + (size_t)col * K + slot * 8);
  }
  __syncthreads();
  int lane = threadIdx.x & 63, wid = threadIdx.x >> 6;
  int l15 = lane & 15, l4 = lane >> 4;
  int n0 = blockIdx.x * 64 + wid * 16;
  f32x4 acc[NCT];
  #pragma unroll
  for (int ct = 0; ct < NCT; ++ct) { f32x4 z = {0.f, 0.f, 0.f, 0.f}; acc[ct] = z; }
  int ar = n0 + l15; if (ar >= M) ar = M - 1;
  #pragma unroll
  for (int kk = 0; kk < KS; ++kk) {
    short8 af = *(const short8*)(A + (size_t)ar * K + kk * 32 + l4 * 8);
    #pragma unroll
    for (int ct = 0; ct < NCT; ++ct) {
      int col = ct * 16 + l15;
      int phys = (kk * 4 + l4) ^ (col & 7);
      short8 bfr = *(const short8*)&wlds[(col * SSTR + phys) * 8];
      acc[ct] = __builtin_amdgcn_mfma_f32_16x16x32_bf16(af, bfr, acc[ct], 0, 0, 0);
    }
  }
  #pragma unroll
  for (int ct = 0; ct < NCT; ++ct) {
    int col = ct * 16 + l15;
    #pragma unroll
    for (int j = 0; j < 4; ++j) {
      int n = n0 + l4 * 4 + j;
      if (n < M) {
        float v = acc[ct][j] + bias[col];
        if (BF16OUT) ((unsigned short*)Cv)[(size_t)n * (NCT * 16) + col] = f2bf(v);
        else         ((float*)Cv)[(size_t)n * (NCT * 16) + col] = v;
      }
    }
  }
}

// ---------------- embed input/weight casts (pad K to 224) --------------------------------
__global__ void cast_atom_kernel(const float* __restrict__ atom, unsigned short* __restrict__ ab,
                                 int N, int AIN) {
  int n = blockIdx.x, k = threadIdx.x;
  if (n < N && k < 224)
    ab[(size_t)n * 224 + k] = f2bf(k < AIN ? atom[(size_t)n * AIN + k] : 0.f);
}
__global__ void prep_we_kernel(const float* __restrict__ W, unsigned short* __restrict__ Bt,
                               int AIN) {
  int i = blockIdx.x * 256 + threadIdx.x;
  if (i >= 128 * 224) return;
  int col = i / 224, k = i % 224;
  Bt[i] = f2bf(k < AIN ? W[(size_t)k * 128 + col] : 0.f);
}

// ---------------- per-feature sum/sumsq over rows (f32 input) ----------------------------
__global__ void colstats_kernel(const float* __restrict__ in, int M, float* __restrict__ stats) {
  int f = threadIdx.x & 127;
  int rl = threadIdx.x >> 7;
  float s = 0, s2 = 0;
  for (int r = blockIdx.x * 2 + rl; r < M; r += gridDim.x * 2) {
    float v = in[(size_t)r * 128 + f];
    s += v; s2 += v * v;
  }
  __shared__ float l1[256], l2[256];
  l1[threadIdx.x] = s; l2[threadIdx.x] = s2;
  __syncthreads();
  if (rl == 0) {
    atomicAdd(&stats[f],       s  + l1[128 + f]);
    atomicAdd(&stats[128 + f], s2 + l2[128 + f]);
  }
}

// ---------------- BN (+silu / +residual), writes f32 x and bf16 xb -----------------------
template<bool SILU, bool RES>
__global__ void bn_act_kernel(const float* __restrict__ in, const float* __restrict__ stats,
                              const float* __restrict__ g, const float* __restrict__ be,
                              const float* __restrict__ resid, float invM,
                              float* __restrict__ xout, unsigned short* __restrict__ xbout,
                              size_t total) {
  int f = threadIdx.x & 127;
  float mean = stats[f] * invM;
  float var  = stats[128 + f] * invM - mean * mean;
  float sc = g[f] * rsqrtf(var + 1e-5f);
  float sh = be[f] - mean * sc;
  for (size_t i = (size_t)blockIdx.x * blockDim.x + threadIdx.x; i < total;
       i += (size_t)gridDim.x * blockDim.x) {
    float v = in[i] * sc + sh;
    if (SILU) v = siluf(v);
    if (RES)  v += resid[i];
    xout[i] = v;
    xbout[i] = f2bf(v);
  }
}

// ---------------- CSR build: histogram, scan, scatter ------------------------------------
__global__ void hist_kernel(const int* __restrict__ ids, int* __restrict__ deg, int E) {
  for (int e = blockIdx.x * blockDim.x + threadIdx.x; e < E; e += gridDim.x * blockDim.x)
    atomicAdd(&deg[ids[e]], 1);
}

__global__ void scan_block_kernel(const int* __restrict__ in, int n,
                                  int* __restrict__ excl, int* __restrict__ totals) {
  __shared__ int tmp[256];
  int idx = blockIdx.x * 256 + threadIdx.x;
  int v = (idx < n) ? in[idx] : 0;
  tmp[threadIdx.x] = v;
  __syncthreads();
  for (int o = 1; o < 256; o <<= 1) {
    int t = (threadIdx.x >= o) ? tmp[threadIdx.x - o] : 0;
    __syncthreads();
    tmp[threadIdx.x] += t;
    __syncthreads();
  }
  if (idx < n) excl[idx] = tmp[threadIdx.x] - v;
  if (threadIdx.x == 255 && totals) totals[blockIdx.x] = tmp[255];
}

__global__ void scan_add_kernel(const int* __restrict__ excl, const int* __restrict__ tot_excl,
                                const int* __restrict__ indeg, int* __restrict__ cstart, int n) {
  int idx = blockIdx.x * 256 + threadIdx.x;
  if (idx < n) {
    int v = excl[idx] + tot_excl[blockIdx.x];
    cstart[idx] = v;
    if (idx == n - 1) cstart[n] = v + indeg[idx];
  }
}

__global__ void scatter_kernel(const int* __restrict__ src, const int* __restrict__ dst,
                               const int* __restrict__ cstart, int* __restrict__ fill,
                               int* __restrict__ csrc, int* __restrict__ cdst, int E) {
  for (int e = blockIdx.x * blockDim.x + threadIdx.x; e < E; e += gridDim.x * blockDim.x) {
    int d = dst[e];
    int pos = cstart[d] + atomicAdd(&fill[d], 1);
    csrc[pos] = src[e];
    cdst[pos] = d;
  }
}

// ---------------- weight preps (bf16, [col][k] layout) -----------------------------------
__global__ void prep_wg_kernel(const float* __restrict__ WgL, const float* __restrict__ bgL,
                               unsigned short* __restrict__ Bt, float* __restrict__ bias) {
  int i = blockIdx.x * 256 + threadIdx.x;
  if (i < 256 * 128) {
    int col = i >> 7, k = i & 127;
    int c = col & 127, h = c >> 5, d = c & 31;
    int krow = (col < 128) ? k : 128 + k;
    Bt[i] = f2bf(WgL[((size_t)h * 256 + krow) * 32 + d]);
  }
  if (i < 256) bias[i] = (i < 128) ? 0.f : bgL[i - 128];
}

__global__ void prep_mv_kernel(const float* __restrict__ Wm, const float* __restrict__ Wv,
                               const float* __restrict__ bm, const float* __restrict__ bv,
                               unsigned short* __restrict__ Bt, float* __restrict__ bias) {
  int i = blockIdx.x * 256 + threadIdx.x;
  if (i < 256 * 128) {
    int col = i >> 7, k = i & 127;
    Bt[i] = f2bf(col < 128 ? Wm[(size_t)k * 128 + col] : Wv[(size_t)k * 128 + col - 128]);
  }
  if (i < 256) bias[i] = (i < 128) ? bm[i] : bv[i - 128];
}

// ---------------- pq (bf16 input) + gate-BN node stats (block-reduced atomics) -----------
__global__ void pq_kernel(const unsigned short* __restrict__ xb, const float* __restrict__ WfL,
                          const float* __restrict__ bfL, const int* __restrict__ indeg,
                          const int* __restrict__ outdeg, float* __restrict__ p,
                          float* __restrict__ q, float* __restrict__ gstats, int N) {
  __shared__ float wf[256];
  __shared__ float red1[4], red2[4];
  wf[threadIdx.x] = WfL[threadIdx.x];
  __syncthreads();
  int wid = threadIdx.x >> 6, lane = threadIdx.x & 63;
  int f0 = lane * 2;
  float bf0 = bfL[0];
  float t1 = 0, t2 = 0;
  for (int n = blockIdx.x * 4 + wid; n < N; n += gridDim.x * 4) {
    unsigned xv = *(const unsigned*)(xb + ((size_t)n << 7) + f0);
    float x0 = bf2f(xv & 0xffffu), x1 = bf2f(xv >> 16);
    float pp = x0 * wf[f0]       + x1 * wf[f0 + 1];
    float qq = x0 * wf[128 + f0] + x1 * wf[129 + f0];
    #pragma unroll
    for (int o = 32; o; o >>= 1) { pp += __shfl_down(pp, o); qq += __shfl_down(qq, o); }
    if (lane == 0) {
      qq += bf0;
      p[n] = pp; q[n] = qq;
      float od = (float)outdeg[n], id = (float)indeg[n];
      t1 += od * pp + id * qq;
      t2 += od * pp * pp + id * qq * qq;
    }
  }
  if (lane == 0) { red1[wid] = t1; red2[wid] = t2; }
  __syncthreads();
  if (threadIdx.x == 0) {
    atomicAdd(&gstats[0], red1[0] + red1[1] + red1[2] + red1[3]);
    atomicAdd(&gstats[1], red2[0] + red2[1] + red2[2] + red2[3]);
  }
}

// ---------------- z-stats node-factorable part -------------------------------------------
__global__ void zstat_node_kernel(const unsigned short* __restrict__ UVb,
                                  const int* __restrict__ indeg, const int* __restrict__ outdeg,
                                  float* __restrict__ zstats, int N) {
  int lane = threadIdx.x & 63, g = threadIdx.x >> 6;
  int f0 = lane * 2, f1 = f0 + 1;
  float zs0 = 0, zq0 = 0, zs1 = 0, zq1 = 0;
  for (int n = blockIdx.x * 4 + g; n < N; n += gridDim.x * 4) {
    float od = (float)outdeg[n], id = (float)indeg[n];
    unsigned up = *(const unsigned*)(UVb + ((size_t)n << 8) + f0);
    unsigned vp = *(const unsigned*)(UVb + ((size_t)n << 8) + 128 + f0);
    float u0 = bf2f(up & 0xffffu), u1 = bf2f(up >> 16);
    float v0 = bf2f(vp & 0xffffu), v1 = bf2f(vp >> 16);
    zs0 += od * u0 + id * v0;  zq0 += od * u0 * u0 + id * v0 * v0;
    zs1 += od * u1 + id * v1;  zq1 += od * u1 * u1 + id * v1 * v1;
  }
  __shared__ float r1[4][128], r2[4][128];
  r1[g][f0] = zs0; r1[g][f1] = zs1;
  r2[g][f0] = zq0; r2[g][f1] = zq1;
  __syncthreads();
  if (threadIdx.x < 128) {
    int f = threadIdx.x;
    atomicAdd(&zstats[f],       r1[0][f] + r1[1][f] + r1[2][f] + r1[3][f]);
    atomicAdd(&zstats[128 + f], r2[0][f] + r2[1][f] + r2[2][f] + r2[3][f]);
  }
}

// ---------------- cross walk: z-cross per feature + gate cross scalar --------------------
// zc[f] += sum_e U[src,f]*V[dst,f]; gc_parts[slot] += sum_e p[src]*q[dst]  (block-reduced)
__global__ void xwalk_kernel(const unsigned short* __restrict__ UVb,
                             const int* __restrict__ csrc, const int* __restrict__ cdst,
                             const float* __restrict__ p, const float* __restrict__ q,
                             float* __restrict__ zc_parts, float* __restrict__ gc_parts, int E) {
  int lane = threadIdx.x & 63, wid = threadIdx.x >> 6;
  int gw = (blockIdx.x * 256 + threadIdx.x) >> 6;
  int nw = (gridDim.x * 256) >> 6;
  int f0 = lane * 2;
  float cr0 = 0, cr1 = 0, gc = 0;
  int nch = (E + 63) >> 6;
  for (int c = gw; c < nch; c += nw) {
    int e0 = c << 6, len = min(64, E - e0);
    int ee = e0 + (lane < len ? lane : len - 1);
    int idxs = csrc[ee], idxd = cdst[ee];
    if (lane < len) gc += p[idxs] * q[idxd];
    int dcur = __shfl(idxd, 0);
    float su0 = 0, su1 = 0;
    const unsigned short* base = UVb;
    #define LDU(i) (*(const unsigned*)(base + ((size_t)__shfl(idxs, (i) < len ? (i) : len - 1) << 8) + f0))
    unsigned a0 = LDU(0), a1 = LDU(1), a2 = LDU(2), a3 = LDU(3);
    for (int bs = 0; bs < len; bs += 4) {
      unsigned b0 = LDU(bs + 4), b1 = LDU(bs + 5), b2 = LDU(bs + 6), b3 = LDU(bs + 7);
      #define PROCX(i, up) if ((i) < len) {                                        \
        int d = __shfl(idxd, (i));                                                 \
        if (d != dcur) {                                                           \
          unsigned vp = *(const unsigned*)(base + ((size_t)dcur << 8) + 128 + f0); \
          cr0 += bf2f(vp & 0xffffu) * su0; cr1 += bf2f(vp >> 16) * su1;            \
          su0 = su1 = 0; dcur = d;                                                 \
        }                                                                          \
        su0 += bf2f((up) & 0xffffu); su1 += bf2f((up) >> 16); }
      PROCX(bs + 0, a0); PROCX(bs + 1, a1); PROCX(bs + 2, a2); PROCX(bs + 3, a3);
      a0 = b0; a1 = b1; a2 = b2; a3 = b3;
    }
    unsigned vp = *(const unsigned*)(base + ((size_t)dcur << 8) + 128 + f0);
    cr0 += bf2f(vp & 0xffffu) * su0; cr1 += bf2f(vp >> 16) * su1;
    #undef PROCX
    #undef LDU
  }
  // block-level reduction before any global atomics
  __shared__ float r1[4][128], rg[4];
  #pragma unroll
  for (int o = 32; o; o >>= 1) gc += __shfl_down(gc, o);
  if (lane == 0) rg[wid] = gc;
  r1[wid][f0] = cr0; r1[wid][f0 + 1] = cr1;
  __syncthreads();
  if (threadIdx.x < 128) {
    int f = threadIdx.x;
    atomicAdd(&zc_parts[(blockIdx.x & 31) * 128 + f], r1[0][f] + r1[1][f] + r1[2][f] + r1[3][f]);
  }
  if (threadIdx.x == 0)
    atomicAdd(&gc_parts[blockIdx.x & 31], rg[0] + rg[1] + rg[2] + rg[3]);
}

// ---------------- gate apply: edge-parallel, per-lane sum_w atomics ----------------------
__global__ void gate_wexp_kernel(const int* __restrict__ csrc, const int* __restrict__ cdst,
                                 const float* __restrict__ p, const float* __restrict__ q,
                                 const float* __restrict__ nodew, const float* __restrict__ gstats,
                                 const float* __restrict__ gc_parts,
                                 const float* __restrict__ gfL, const float* __restrict__ befL,
                                 float* __restrict__ wexp, float* __restrict__ sum_w,
                                 int E, float invE) {
  float gcr = 0;
  #pragma unroll
  for (int i = 0; i < 32; ++i) gcr += gc_parts[i];
  float gm  = gstats[0] * invE;
  float gv  = (gstats[1] + 2.f * gcr) * invE - gm * gm;
  float gsc = gfL[0] * rsqrtf(gv + 1e-5f);
  float gsh = befL[0] - gm * gsc;
  for (int e = blockIdx.x * blockDim.x + threadIdx.x; e < E; e += gridDim.x * blockDim.x) {
    int s = csrc[e], d = cdst[e];
    float v = (p[s] + q[d]) * gsc + gsh;
    v = v * frcp(1.f + fexp(-v));
    float we = nodew[s] * fexp(v);
    wexp[e] = we;
    atomicAdd(&sum_w[d], we);
  }
}

// ---------------- aggregate: edge-parallel, 4-deep prefetch, register segments -----------
__global__ void walk2_kernel(const unsigned short* __restrict__ UVb,
                             const int* __restrict__ csrc, const int* __restrict__ cdst,
                             const float* __restrict__ wexp, const float* __restrict__ sum_w,
                             const float* __restrict__ zstats, const float* __restrict__ zc_parts,
                             const float* __restrict__ gg, const float* __restrict__ beg,
                             float* __restrict__ h, int E, float invE) {
  int lane = threadIdx.x & 63;
  int gw = (blockIdx.x * 256 + threadIdx.x) >> 6;
  int nw = (gridDim.x * 256) >> 6;
  int f0 = lane * 2, f1 = f0 + 1;
  float cr0 = 0, cr1 = 0;
  #pragma unroll
  for (int i2 = 0; i2 < 32; ++i2) { cr0 += zc_parts[i2 * 128 + f0]; cr1 += zc_parts[i2 * 128 + f1]; }
  float zm0 = zstats[f0] * invE;
  float zv0 = (zstats[128 + f0] + 2.f * cr0) * invE - zm0 * zm0;
  float sc0 = gg[f0] * rsqrtf(zv0 + 1e-5f), sh0 = beg[f0] - zm0 * sc0;
  float zm1 = zstats[f1] * invE;
  float zv1 = (zstats[128 + f1] + 2.f * cr1) * invE - zm1 * zm1;
  float sc1 = gg[f1] * rsqrtf(zv1 + 1e-5f), sh1 = beg[f1] - zm1 * sc1;

  int nch = (E + 63) >> 6;
  for (int c = gw; c < nch; c += nw) {
    int e0 = c << 6, len = min(64, E - e0);
    int ee = e0 + (lane < len ? lane : len - 1);
    int idxs = csrc[ee], idxd = cdst[ee];
    float wv = wexp[ee];
    int dcur = __shfl(idxd, 0);
    float inv = frcp(sum_w[dcur]);
    float c0, c1;
    { unsigned vp = *(const unsigned*)(UVb + ((size_t)dcur << 8) + 128 + f0);
      c0 = bf2f(vp & 0xffffu) * sc0 + sh0; c1 = bf2f(vp >> 16) * sc1 + sh1; }
    float h0 = 0, h1 = 0;
    #define LDU(i) (*(const unsigned*)(UVb + ((size_t)__shfl(idxs, (i) < len ? (i) : len - 1) << 8) + f0))
    unsigned a0 = LDU(0), a1 = LDU(1), a2 = LDU(2), a3 = LDU(3);
    for (int bs = 0; bs < len; bs += 4) {
      unsigned b0 = LDU(bs + 4), b1 = LDU(bs + 5), b2 = LDU(bs + 6), b3 = LDU(bs + 7);
      #define PROCW(i, up) if ((i) < len) {                                          \
        int d = __shfl(idxd, (i));                                                   \
        float a = __shfl(wv, (i));                                                   \
        if (d != dcur) {                                                             \
          atomicAdd(&h[((size_t)dcur << 7) + f0], h0 * inv);                         \
          atomicAdd(&h[((size_t)dcur << 7) + f1], h1 * inv);                         \
          h0 = h1 = 0; dcur = d; inv = frcp(sum_w[d]);                               \
          unsigned vp = *(const unsigned*)(UVb + ((size_t)d << 8) + 128 + f0);       \
          c0 = bf2f(vp & 0xffffu) * sc0 + sh0; c1 = bf2f(vp >> 16) * sc1 + sh1;      \
        }                                                                            \
        float v0 = bf2f((up) & 0xffffu) * sc0 + c0;                                  \
        float v1 = bf2f((up) >> 16)     * sc1 + c1;                                  \
        v0 = v0 * frcp(1.f + fexp(-v0));                                             \
        v1 = v1 * frcp(1.f + fexp(-v1));                                             \
        h0 += a * v0; h1 += a * v1; }
      PROCW(bs + 0, a0); PROCW(bs + 1, a1); PROCW(bs + 2, a2); PROCW(bs + 3, a3);
      a0 = b0; a1 = b1; a2 = b2; a3 = b3;
    }
    atomicAdd(&h[((size_t)dcur << 7) + f0], h0 * inv);
    atomicAdd(&h[((size_t)dcur << 7) + f1], h1 * inv);
    #undef PROCW
    #undef LDU
  }
}

// ---------------- reparameterize (bf16 muv=[mu|lv] packed [N,256]) + kld -----------------
__global__ void reparam_kernel(const unsigned short* __restrict__ muv,
                               const float* __restrict__ eps,
                               float* __restrict__ x, unsigned short* __restrict__ xb,
                               float* __restrict__ kacc, size_t total) {
  float part = 0;
  for (size_t i = (size_t)blockIdx.x * blockDim.x + threadIdx.x; i < total;
       i += (size_t)gridDim.x * blockDim.x) {
    size_t n = i >> 7; int f = (int)(i & 127);
    float m = bf2f(muv[(n << 8) + f]);
    float l = bf2f(muv[(n << 8) + 128 + f]);
    float el = fexp(l);
    float v = eps[i] * fexp(0.5f * l) + m;
    x[i] = v;
    xb[i] = f2bf(v);
    part += 1.f + l - m * m - el;
  }
  #pragma unroll
  for (int o = 32; o; o >>= 1) part += __shfl_down(part, o);
  __shared__ float la[4];
  int lane = threadIdx.x & 63, wid = threadIdx.x >> 6;
  if (lane == 0) la[wid] = part;
  __syncthreads();
  if (threadIdx.x == 0) atomicAdd(kacc, la[0] + la[1] + la[2] + la[3]);
}

// ---------------- pooling: sorted gid -> run-length segmented wave sum -------------------
__global__ void pool_kernel(const float* __restrict__ x, const int* __restrict__ gid,
                            float* __restrict__ pools, float* __restrict__ cnt, int N) {
  int lane = threadIdx.x & 63;
  int gw = (blockIdx.x * 256 + threadIdx.x) >> 6;
  int nw = (gridDim.x * 256) >> 6;
  int f0 = lane * 2, f1 = f0 + 1;
  const int CH = 64;
  int nch = (N + CH - 1) / CH;
  for (int c = gw; c < nch; c += nw) {
    int n0 = c * CH, n1 = min(N, n0 + CH);
    int gcur = gid[n0];
    float a0 = 0, a1 = 0, count = 0;
    for (int n = n0; n < n1; ++n) {
      int g = gid[n];
      if (g != gcur) {
        atomicAdd(&pools[((size_t)gcur << 7) + f0], a0);
        atomicAdd(&pools[((size_t)gcur << 7) + f1], a1);
        if (lane == 0) atomicAdd(&cnt[gcur], count);
        a0 = a1 = 0; count = 0; gcur = g;
      }
      float2 xv = *(const float2*)(x + ((size_t)n << 7) + f0);
      a0 += xv.x; a1 += xv.y; count += 1.f;
    }
    atomicAdd(&pools[((size_t)gcur << 7) + f0], a0);
    atomicAdd(&pools[((size_t)gcur << 7) + f1], a1);
    if (lane == 0) atomicAdd(&cnt[gcur], count);
  }
}

__global__ void finalize_kernel(const float* __restrict__ pools, const float* __restrict__ cnt,
                                const float* __restrict__ kacc, float* __restrict__ out,
                                int NG, float invN) {
  int i = blockIdx.x * blockDim.x + threadIdx.x;
  if (i < NG * 128) {
    float c = cnt[i >> 7];
    c = c > 1.f ? c : 1.f;
    out[i] = pools[i] / c;
  }
  if (i == 0) out[NG * 128] = -0.5f * kacc[0] * invN;
}

// =========================================================================================
extern "C" void kernel_launch(void* const* d_in, const int* in_sizes, int n_in,
                              void* d_out, int out_size, void* d_ws, size_t ws_size,
                              hipStream_t stream) {
  const float* atom    = (const float*)d_in[0];
  const float* nodew   = (const float*)d_in[1];
  const float* epsp    = (const float*)d_in[2];
  const int*   src     = (const int*)d_in[3];
  const int*   dst     = (const int*)d_in[4];
  const int*   gid     = (const int*)d_in[5];
  const float* W_embed = (const float*)d_in[6];
  const float* b_embed = (const float*)d_in[7];
  const float* g_embed = (const float*)d_in[8];
  const float* be_embed= (const float*)d_in[9];
  const float* Wf      = (const float*)d_in[10];
  const float* bfp     = (const float*)d_in[11];
  const float* gfp     = (const float*)d_in[12];
  const float* befp    = (const float*)d_in[13];
  const float* Wg      = (const float*)d_in[14];
  const float* bg      = (const float*)d_in[15];
  const float* gg      = (const float*)d_in[16];
  const float* beg     = (const float*)d_in[17];
  const float* gn      = (const float*)d_in[18];
  const float* ben     = (const float*)d_in[19];
  const float* W_mu    = (const float*)d_in[20];
  const float* b_mu    = (const float*)d_in[21];
  const float* W_var   = (const float*)d_in[22];
  const float* b_var   = (const float*)d_in[23];

  const int N   = in_sizes[1];
  const int E   = in_sizes[3];
  const int AIN = in_sizes[0] / N;
  const int NG  = (out_size - 1) / HID;

  char* w = (char*)d_ws;
  size_t off = 0;
  auto alloc = [&](size_t bytes) { size_t r = off; off = (off + bytes + 255) & ~(size_t)255; return r; };
  size_t o_x    = alloc((size_t)N*HID*4);
  size_t o_xb   = alloc((size_t)N*HID*2);
  size_t o_uvb  = alloc((size_t)N*256*2);
  size_t o_h    = alloc((size_t)N*HID*4);
  size_t o_ab   = alloc((size_t)N*224*2);
  size_t o_p    = alloc((size_t)N*4);
  size_t o_q    = alloc((size_t)N*4);
  size_t o_sw   = alloc((size_t)N*4);
  size_t o_wexp = alloc((size_t)E*4);
  size_t o_csrc = alloc((size_t)E*4);
  size_t o_cdst = alloc((size_t)E*4);
  size_t o_cs   = alloc((size_t)(N+1)*4);
  size_t o_deg  = alloc((size_t)3*N*4);      // indeg | fill | outdeg
  size_t o_excl = alloc((size_t)N*4);
  size_t o_tot  = alloc(512*4);
  size_t o_bt   = alloc((size_t)256*128*2);
  size_t o_bias = alloc(256*4);
  // stats layout: [0:2) gate sum/nodesq; [2:34) gc_parts; [34:290) z; [290:546) node; [546:546+4096) zc_parts
  size_t o_st   = alloc((546 + 32*128)*4);
  size_t o_kp   = alloc((size_t)(64 + NG*HID + NG)*4);

  float* x              = (float*)(w + o_x);
  unsigned short* xb    = (unsigned short*)(w + o_xb);
  unsigned short* UVb   = (unsigned short*)(w + o_uvb);
  float* h              = (float*)(w + o_h);
  unsigned short* atomb = (unsigned short*)(w + o_ab);
  float* p              = (float*)(w + o_p);
  float* q              = (float*)(w + o_q);
  float* sum_w          = (float*)(w + o_sw);
  float* wexp           = (float*)(w + o_wexp);
  int*   csrc           = (int*)(w + o_csrc);
  int*   cdst           = (int*)(w + o_cdst);
  int*   cstart         = (int*)(w + o_cs);
  int*   indeg          = (int*)(w + o_deg);
  int*   fill           = indeg + N;
  int*   outdeg         = indeg + 2*N;
  int*   excl           = (int*)(w + o_excl);
  int*   totals         = (int*)(w + o_tot);
  int*   tot_excl       = totals + 256;
  unsigned short* Bt    = (unsigned short*)(w + o_bt);
  float* bias           = (float*)(w + o_bias);
  float* stats          = (float*)(w + o_st);
  float* gstats         = stats;
  float* gc_parts       = stats + 2;
  float* zstats         = stats + 34;
  float* nstats         = stats + 290;
  float* zc_parts       = stats + 546;
  float* kacc           = (float*)(w + o_kp);
  float* pools          = kacc + 64;
  float* cnt            = pools + (size_t)NG*HID;

  const dim3 B(256);
  const int mblk = (N + 63) / 64;
  const int nb1  = (N + 255) / 256;
  const float invN = 1.f / (float)N;
  const float invE = 1.f / (float)E;
  const size_t totalNH = (size_t)N * HID;
  const size_t st_bytes = (546 + 32*128) * 4;

  // ---- zero accumulators ----
  hipMemsetAsync(w + o_st, 0, st_bytes, stream);
  hipMemsetAsync(w + o_kp, 0, (64 + (size_t)NG*HID + NG)*4, stream);
  hipMemsetAsync(w + o_deg, 0, (size_t)3*N*4, stream);

  // ---- CSR build (dst-sorted) + degrees ----
  hist_kernel<<<dim3(1024), B, 0, stream>>>(dst, indeg, E);
  hist_kernel<<<dim3(1024), B, 0, stream>>>(src, outdeg, E);
  scan_block_kernel<<<dim3(nb1), B, 0, stream>>>(indeg, N, excl, totals);
  scan_block_kernel<<<dim3(1), B, 0, stream>>>(totals, nb1, tot_excl, nullptr);
  scan_add_kernel<<<dim3(nb1), B, 0, stream>>>(excl, tot_excl, indeg, cstart, N);
  scatter_kernel<<<dim3(1024), B, 0, stream>>>(src, dst, cstart, fill, csrc, cdst, E);

  // ---- atom embedding ----
  cast_atom_kernel<<<dim3(N), B, 0, stream>>>(atom, atomb, N, AIN);
  prep_we_kernel<<<dim3(112), B, 0, stream>>>(W_embed, Bt, AIN);
  gemm_bf16_kernel<7, 8, false><<<dim3(mblk), B, 0, stream>>>(atomb, Bt, b_embed, h, N);
  colstats_kernel<<<dim3(512), B, 0, stream>>>(h, N, nstats);
  bn_act_kernel<true,false><<<dim3(2048), B, 0, stream>>>(h, nstats, g_embed, be_embed,
                                                          x, invN, x, xb, totalNH);

  for (int l = 0; l < LAYERS; ++l) {
    if (l == 1) {
      prep_mv_kernel<<<dim3(128), B, 0, stream>>>(W_mu, W_var, b_mu, b_var, Bt, bias);
      gemm_bf16_kernel<4, 16, true><<<dim3(mblk), B, 0, stream>>>(xb, Bt, bias, UVb, N);
      reparam_kernel<<<dim3(2048), B, 0, stream>>>(UVb, epsp, x, xb, kacc, totalNH);
    }
    prep_wg_kernel<<<dim3(128), B, 0, stream>>>(Wg + (size_t)l*4*256*32, bg + l*128, Bt, bias);
    hipMemsetAsync(w + o_st, 0, st_bytes, stream);
    hipMemsetAsync(w + o_h, 0, (size_t)N*HID*4, stream);
    hipMemsetAsync(w + o_sw, 0, (size_t)N*4, stream);
    gemm_bf16_kernel<4, 16, true><<<dim3(mblk), B, 0, stream>>>(xb, Bt, bias, UVb, N);
    pq_kernel<<<dim3(512), B, 0, stream>>>(xb, Wf + l*256, bfp + l, indeg, outdeg,
                                           p, q, gstats, N);
    xwalk_kernel<<<dim3(2048), B, 0, stream>>>(UVb, csrc, cdst, p, q, zc_parts, gc_parts, E);
    zstat_node_kernel<<<dim3(512), B, 0, stream>>>(UVb, indeg, outdeg, zstats, N);
    gate_wexp_kernel<<<dim3(1024), B, 0, stream>>>(csrc, cdst, p, q, nodew, gstats, gc_parts,
                                                   gfp + l, befp + l, wexp, sum_w, E, invE);
    walk2_kernel<<<dim3(2048), B, 0, stream>>>(UVb, csrc, cdst, wexp, sum_w, zstats, zc_parts,
                                               gg + l*128, beg + l*128, h, E, invE);
    colstats_kernel<<<dim3(512), B, 0, stream>>>(h, N, nstats);
    bn_act_kernel<false,true><<<dim3(2048), B, 0, stream>>>(h, nstats, gn + l*128, ben + l*128,
                                                            x, invN, x, xb, totalNH);
  }

  // ---- pooling + output ----
  pool_kernel<<<dim3(256), B, 0, stream>>>(x, gid, pools, cnt, N);
  finalize_kernel<<<dim3((NG*HID + 255)/256), B, 0, stream>>>(pools, cnt, kacc,
                                                              (float*)d_out, NG, invN);
}

// Round 9
// 1858.946 us; speedup vs baseline: 1.8120x; 1.0924x over previous
//
#include <hip/hip_runtime.h>
#include <hip/hip_bf16.h>
#include <stdint.h>

#define HID 128
#define LAYERS 5

typedef __attribute__((ext_vector_type(8))) short short8;
typedef __attribute__((ext_vector_type(4))) float f32x4;

__device__ __forceinline__ float bf2f(unsigned int u16) {
  union { unsigned int i; float f; } c; c.i = u16 << 16; return c.f;
}
__device__ __forceinline__ unsigned short f2bf(float f) {
  union { float f; unsigned int i; } c; c.f = f;
  unsigned int r = c.i + 0x7fffu + ((c.i >> 16) & 1u);
  return (unsigned short)(r >> 16);
}
__device__ __forceinline__ float fexp(float x) {
  float r; asm("v_exp_f32 %0, %1" : "=v"(r) : "v"(x * 1.44269504f)); return r;
}
__device__ __forceinline__ float frcp(float x) {
  float r; asm("v_rcp_f32 %0, %1" : "=v"(r) : "v"(x)); return r;
}
__device__ __forceinline__ float siluf(float v) { return v * frcp(1.f + fexp(-v)); }

// ---------------- bf16 MFMA GEMM: C[M, NCT*16] = A[M, KS*32] @ Bt^T + bias ---------------
// ZSTAT: additionally accumulate degree-weighted sum/sumsq of C into zstats (UV gemm only)
template<int KS, int NCT, bool BF16OUT, bool ZSTAT>
__launch_bounds__(256)
__global__ void gemm_bf16_kernel(const unsigned short* __restrict__ A,
                                 const unsigned short* __restrict__ Bt,
                                 const float* __restrict__ bias,
                                 void* __restrict__ Cv, int M,
                                 const int* __restrict__ indeg, const int* __restrict__ outdeg,
                                 float* __restrict__ zstats) {
  constexpr int K = KS * 32;
  constexpr int SLOTS = KS * 4;
  constexpr int SSTR = (SLOTS + 7) & ~7;
  __shared__ unsigned short wlds[NCT * 16 * SSTR * 8];
  for (int i = threadIdx.x; i < NCT * 16 * SLOTS; i += 256) {
    int col = i / SLOTS, slot = i % SLOTS;
    int phys = slot ^ (col & 7);
    *(uint4*)&wlds[(col * SSTR + phys) * 8] = *(const uint4*)(Bt + (size_t)col * K + slot * 8);
  }
  __syncthreads();
  int lane = threadIdx.x & 63, wid = threadIdx.x >> 6;
  int l15 = lane & 15, l4 = lane >> 4;
  int n0 = blockIdx.x * 64 + wid * 16;
  f32x4 acc[NCT];
  #pragma unroll
  for (int ct = 0; ct < NCT; ++ct) { f32x4 z = {0.f, 0.f, 0.f, 0.f}; acc[ct] = z; }
  int ar = n0 + l15; if (ar >= M) ar = M - 1;
  #pragma unroll
  for (int kk = 0; kk < KS; ++kk) {
    short8 af = *(const short8*)(A + (size_t)ar * K + kk * 32 + l4 * 8);
    #pragma unroll
    for (int ct = 0; ct < NCT; ++ct) {
      int col = ct * 16 + l15;
      int phys = (kk * 4 + l4) ^ (col & 7);
      short8 bfr = *(const short8*)&wlds[(col * SSTR + phys) * 8];
      acc[ct] = __builtin_amdgcn_mfma_f32_16x16x32_bf16(af, bfr, acc[ct], 0, 0, 0);
    }
  }
  #pragma unroll
  for (int ct = 0; ct < NCT; ++ct) {
    int col = ct * 16 + l15;
    #pragma unroll
    for (int j = 0; j < 4; ++j) {
      int n = n0 + l4 * 4 + j;
      if (n < M) {
        float v = acc[ct][j] + bias[col];
        if (BF16OUT) ((unsigned short*)Cv)[(size_t)n * (NCT * 16) + col] = f2bf(v);
        else         ((float*)Cv)[(size_t)n * (NCT * 16) + col] = v;
      }
    }
  }
  if constexpr (ZSTAT) {
    // reuse wlds as reduce scratch (all LDS reads complete after MFMA loop)
    __syncthreads();
    float* zr = (float*)wlds;          // [512]: [0:256) w-sum per col, [256:512) w-sumsq
    for (int i = threadIdx.x; i < 512; i += 256) zr[i] = 0.f;
    __syncthreads();
    float odj[4], idj[4];
    #pragma unroll
    for (int j = 0; j < 4; ++j) {
      int n = n0 + l4 * 4 + j;
      odj[j] = (n < M) ? (float)outdeg[n] : 0.f;
      idj[j] = (n < M) ? (float)indeg[n]  : 0.f;
    }
    #pragma unroll
    for (int ct = 0; ct < NCT; ++ct) {
      int col = ct * 16 + l15;
      bool isv = col >= 128;
      float s = 0, sq = 0;
      #pragma unroll
      for (int j = 0; j < 4; ++j) {
        float v = acc[ct][j] + bias[col];
        float w = isv ? idj[j] : odj[j];
        s += w * v; sq += w * v * v;
      }
      atomicAdd(&zr[col], s);
      atomicAdd(&zr[256 + col], sq);
    }
    __syncthreads();
    if (threadIdx.x < 128) {
      int f = threadIdx.x;
      atomicAdd(&zstats[f],       zr[f]       + zr[128 + f]);
      atomicAdd(&zstats[128 + f], zr[256 + f] + zr[384 + f]);
    }
  }
}

// ---------------- embed input/weight casts (pad K to 224) --------------------------------
__global__ void cast_atom_kernel(const float* __restrict__ atom, unsigned short* __restrict__ ab,
                                 int N, int AIN) {
  int n = blockIdx.x, k = threadIdx.x;
  if (n < N && k < 224)
    ab[(size_t)n * 224 + k] = f2bf(k < AIN ? atom[(size_t)n * AIN + k] : 0.f);
}
__global__ void prep_we_kernel(const float* __restrict__ W, unsigned short* __restrict__ Bt,
                               int AIN) {
  int i = blockIdx.x * 256 + threadIdx.x;
  if (i >= 128 * 224) return;
  int col = i / 224, k = i % 224;
  Bt[i] = f2bf(k < AIN ? W[(size_t)k * 128 + col] : 0.f);
}

// ---------------- per-feature sum/sumsq over rows; DIV: scale row by 1/sum_w -------------
template<bool DIV>
__global__ void colstats_kernel(const float* __restrict__ in, const float* __restrict__ sum_w,
                                int M, float* __restrict__ stats) {
  int f = threadIdx.x & 127;
  int rl = threadIdx.x >> 7;
  float s = 0, s2 = 0;
  for (int r = blockIdx.x * 2 + rl; r < M; r += gridDim.x * 2) {
    float v = in[(size_t)r * 128 + f];
    if (DIV) {
      float sw = sum_w[r];
      v *= (sw > 0.f) ? frcp(sw) : 0.f;
    }
    s += v; s2 += v * v;
  }
  __shared__ float l1[256], l2[256];
  l1[threadIdx.x] = s; l2[threadIdx.x] = s2;
  __syncthreads();
  if (rl == 0) {
    atomicAdd(&stats[f],       s  + l1[128 + f]);
    atomicAdd(&stats[128 + f], s2 + l2[128 + f]);
  }
}

// ---------------- BN (+silu/+residual/+row-div), writes f32 x and bf16 xb ----------------
template<bool SILU, bool RES, bool DIV>
__global__ void bn_act_kernel(const float* __restrict__ in, const float* __restrict__ sum_w,
                              const float* __restrict__ stats,
                              const float* __restrict__ g, const float* __restrict__ be,
                              const float* __restrict__ resid, float invM,
                              float* __restrict__ xout, unsigned short* __restrict__ xbout,
                              size_t total) {
  int f = threadIdx.x & 127;
  float mean = stats[f] * invM;
  float var  = stats[128 + f] * invM - mean * mean;
  float sc = g[f] * rsqrtf(var + 1e-5f);
  float sh = be[f] - mean * sc;
  for (size_t i = (size_t)blockIdx.x * blockDim.x + threadIdx.x; i < total;
       i += (size_t)gridDim.x * blockDim.x) {
    float hv = in[i];
    if (DIV) {
      float sw = sum_w[i >> 7];
      hv *= (sw > 0.f) ? frcp(sw) : 0.f;
    }
    float v = hv * sc + sh;
    if (SILU) v = siluf(v);
    if (RES)  v += resid[i];
    xout[i] = v;
    xbout[i] = f2bf(v);
  }
}

// ---------------- CSR build: histogram, scan, scatter, run-fill --------------------------
__global__ void hist_kernel(const int* __restrict__ ids, int* __restrict__ deg, int E) {
  for (int e = blockIdx.x * blockDim.x + threadIdx.x; e < E; e += gridDim.x * blockDim.x)
    atomicAdd(&deg[ids[e]], 1);
}

__global__ void scan_block_kernel(const int* __restrict__ in, int n,
                                  int* __restrict__ excl, int* __restrict__ totals) {
  __shared__ int tmp[256];
  int idx = blockIdx.x * 256 + threadIdx.x;
  int v = (idx < n) ? in[idx] : 0;
  tmp[threadIdx.x] = v;
  __syncthreads();
  for (int o = 1; o < 256; o <<= 1) {
    int t = (threadIdx.x >= o) ? tmp[threadIdx.x - o] : 0;
    __syncthreads();
    tmp[threadIdx.x] += t;
    __syncthreads();
  }
  if (idx < n) excl[idx] = tmp[threadIdx.x] - v;
  if (threadIdx.x == 255 && totals) totals[blockIdx.x] = tmp[255];
}

__global__ void scan_add_kernel(const int* __restrict__ excl, const int* __restrict__ tot_excl,
                                const int* __restrict__ indeg, int* __restrict__ cstart, int n) {
  int idx = blockIdx.x * 256 + threadIdx.x;
  if (idx < n) {
    int v = excl[idx] + tot_excl[blockIdx.x];
    cstart[idx] = v;
    if (idx == n - 1) cstart[n] = v + indeg[idx];
  }
}

__global__ void scatter_kernel(const int* __restrict__ src, const int* __restrict__ dst,
                               const int* __restrict__ cstart, int* __restrict__ fill,
                               int* __restrict__ csrc, int E) {
  for (int e = blockIdx.x * blockDim.x + threadIdx.x; e < E; e += gridDim.x * blockDim.x) {
    int d = dst[e];
    int pos = cstart[d] + atomicAdd(&fill[d], 1);
    csrc[pos] = src[e];
  }
}

__global__ void fill_cdst_kernel(const int* __restrict__ cstart, int* __restrict__ cdst, int N) {
  for (int n = blockIdx.x * blockDim.x + threadIdx.x; n < N; n += gridDim.x * blockDim.x) {
    int s0 = cstart[n], s1 = cstart[n + 1];
    for (int j = s0; j < s1; ++j) cdst[j] = n;
  }
}

// ---------------- weight preps (bf16, [col][k] layout) -----------------------------------
__global__ void prep_wg_kernel(const float* __restrict__ WgL, const float* __restrict__ bgL,
                               unsigned short* __restrict__ Bt, float* __restrict__ bias) {
  int i = blockIdx.x * 256 + threadIdx.x;
  if (i < 256 * 128) {
    int col = i >> 7, k = i & 127;
    int c = col & 127, h = c >> 5, d = c & 31;
    int krow = (col < 128) ? k : 128 + k;
    Bt[i] = f2bf(WgL[((size_t)h * 256 + krow) * 32 + d]);
  }
  if (i < 256) bias[i] = (i < 128) ? 0.f : bgL[i - 128];
}

__global__ void prep_mv_kernel(const float* __restrict__ Wm, const float* __restrict__ Wv,
                               const float* __restrict__ bm, const float* __restrict__ bv,
                               unsigned short* __restrict__ Bt, float* __restrict__ bias) {
  int i = blockIdx.x * 256 + threadIdx.x;
  if (i < 256 * 128) {
    int col = i >> 7, k = i & 127;
    Bt[i] = f2bf(col < 128 ? Wm[(size_t)k * 128 + col] : Wv[(size_t)k * 128 + col - 128]);
  }
  if (i < 256) bias[i] = (i < 128) ? bm[i] : bv[i - 128];
}

// ---------------- pq (bf16 input) + gate-BN node stats (block-reduced atomics) -----------
__global__ void pq_kernel(const unsigned short* __restrict__ xb, const float* __restrict__ WfL,
                          const float* __restrict__ bfL, const int* __restrict__ indeg,
                          const int* __restrict__ outdeg, float* __restrict__ p,
                          float* __restrict__ q, float* __restrict__ gstats, int N) {
  __shared__ float wf[256];
  __shared__ float red1[4], red2[4];
  wf[threadIdx.x] = WfL[threadIdx.x];
  __syncthreads();
  int wid = threadIdx.x >> 6, lane = threadIdx.x & 63;
  int f0 = lane * 2;
  float bf0 = bfL[0];
  float t1 = 0, t2 = 0;
  for (int n = blockIdx.x * 4 + wid; n < N; n += gridDim.x * 4) {
    unsigned xv = *(const unsigned*)(xb + ((size_t)n << 7) + f0);
    float x0 = bf2f(xv & 0xffffu), x1 = bf2f(xv >> 16);
    float pp = x0 * wf[f0]       + x1 * wf[f0 + 1];
    float qq = x0 * wf[128 + f0] + x1 * wf[129 + f0];
    #pragma unroll
    for (int o = 32; o; o >>= 1) { pp += __shfl_down(pp, o); qq += __shfl_down(qq, o); }
    if (lane == 0) {
      qq += bf0;
      p[n] = pp; q[n] = qq;
      float od = (float)outdeg[n], id = (float)indeg[n];
      t1 += od * pp + id * qq;
      t2 += od * pp * pp + id * qq * qq;
    }
  }
  if (lane == 0) { red1[wid] = t1; red2[wid] = t2; }
  __syncthreads();
  if (threadIdx.x == 0) {
    atomicAdd(&gstats[0], red1[0] + red1[1] + red1[2] + red1[3]);
    atomicAdd(&gstats[1], red2[0] + red2[1] + red2[2] + red2[3]);
  }
}

// ---------------- cross walk: z-cross per feature + gate cross scalar --------------------
__global__ void xwalk_kernel(const unsigned short* __restrict__ UVb,
                             const int* __restrict__ csrc, const int* __restrict__ cdst,
                             const float* __restrict__ p, const float* __restrict__ q,
                             float* __restrict__ zc_parts, float* __restrict__ gc_parts, int E) {
  int lane = threadIdx.x & 63, wid = threadIdx.x >> 6;
  int gw = (blockIdx.x * 256 + threadIdx.x) >> 6;
  int nw = (gridDim.x * 256) >> 6;
  int f0 = lane * 2;
  float cr0 = 0, cr1 = 0, gc = 0;
  int nch = (E + 63) >> 6;
  for (int c = gw; c < nch; c += nw) {
    int e0 = c << 6, len = min(64, E - e0);
    int ee = e0 + (lane < len ? lane : len - 1);
    int idxs = csrc[ee], idxd = cdst[ee];
    if (lane < len) gc += p[idxs] * q[idxd];
    int dcur = __shfl(idxd, 0);
    float su0 = 0, su1 = 0;
    const unsigned short* base = UVb;
    #define LDU(i) (*(const unsigned*)(base + ((size_t)__shfl(idxs, (i) < len ? (i) : len - 1) << 8) + f0))
    unsigned a0 = LDU(0), a1 = LDU(1), a2 = LDU(2), a3 = LDU(3);
    for (int bs = 0; bs < len; bs += 4) {
      unsigned b0 = LDU(bs + 4), b1 = LDU(bs + 5), b2 = LDU(bs + 6), b3 = LDU(bs + 7);
      #define PROCX(i, up) if ((i) < len) {                                        \
        int d = __shfl(idxd, (i));                                                 \
        if (d != dcur) {                                                           \
          unsigned vp = *(const unsigned*)(base + ((size_t)dcur << 8) + 128 + f0); \
          cr0 += bf2f(vp & 0xffffu) * su0; cr1 += bf2f(vp >> 16) * su1;            \
          su0 = su1 = 0; dcur = d;                                                 \
        }                                                                          \
        su0 += bf2f((up) & 0xffffu); su1 += bf2f((up) >> 16); }
      PROCX(bs + 0, a0); PROCX(bs + 1, a1); PROCX(bs + 2, a2); PROCX(bs + 3, a3);
      a0 = b0; a1 = b1; a2 = b2; a3 = b3;
    }
    unsigned vp = *(const unsigned*)(base + ((size_t)dcur << 8) + 128 + f0);
    cr0 += bf2f(vp & 0xffffu) * su0; cr1 += bf2f(vp >> 16) * su1;
    #undef PROCX
    #undef LDU
  }
  __shared__ float r1[4][128], rg[4];
  #pragma unroll
  for (int o = 32; o; o >>= 1) gc += __shfl_down(gc, o);
  if (lane == 0) rg[wid] = gc;
  r1[wid][f0] = cr0; r1[wid][f0 + 1] = cr1;
  __syncthreads();
  if (threadIdx.x < 128) {
    int f = threadIdx.x;
    atomicAdd(&zc_parts[(blockIdx.x & 31) * 128 + f], r1[0][f] + r1[1][f] + r1[2][f] + r1[3][f]);
  }
  if (threadIdx.x == 0)
    atomicAdd(&gc_parts[blockIdx.x & 31], rg[0] + rg[1] + rg[2] + rg[3]);
}

// ---------------- fused walk: gate + wexp in-register + h_raw aggregate + sum_w ----------
__global__ void walk2_kernel(const unsigned short* __restrict__ UVb,
                             const int* __restrict__ csrc, const int* __restrict__ cdst,
                             const float* __restrict__ p, const float* __restrict__ q,
                             const float* __restrict__ nodew,
                             const float* __restrict__ gstats, const float* __restrict__ gc_parts,
                             const float* __restrict__ gfL, const float* __restrict__ befL,
                             const float* __restrict__ zstats, const float* __restrict__ zc_parts,
                             const float* __restrict__ gg, const float* __restrict__ beg,
                             float* __restrict__ h, float* __restrict__ sum_w,
                             int E, float invE) {
  int lane = threadIdx.x & 63;
  int gw = (blockIdx.x * 256 + threadIdx.x) >> 6;
  int nw = (gridDim.x * 256) >> 6;
  int f0 = lane * 2, f1 = f0 + 1;
  // gate BN coefficients
  float gcr = 0;
  #pragma unroll
  for (int i = 0; i < 32; ++i) gcr += gc_parts[i];
  float gm  = gstats[0] * invE;
  float gv  = (gstats[1] + 2.f * gcr) * invE - gm * gm;
  float gsc = gfL[0] * rsqrtf(gv + 1e-5f);
  float gsh = befL[0] - gm * gsc;
  // z BN coefficients (per feature pair)
  float cr0 = 0, cr1 = 0;
  #pragma unroll
  for (int i2 = 0; i2 < 32; ++i2) { cr0 += zc_parts[i2 * 128 + f0]; cr1 += zc_parts[i2 * 128 + f1]; }
  float zm0 = zstats[f0] * invE;
  float zv0 = (zstats[128 + f0] + 2.f * cr0) * invE - zm0 * zm0;
  float sc0 = gg[f0] * rsqrtf(zv0 + 1e-5f), sh0 = beg[f0] - zm0 * sc0;
  float zm1 = zstats[f1] * invE;
  float zv1 = (zstats[128 + f1] + 2.f * cr1) * invE - zm1 * zm1;
  float sc1 = gg[f1] * rsqrtf(zv1 + 1e-5f), sh1 = beg[f1] - zm1 * sc1;

  int nch = (E + 63) >> 6;
  for (int c = gw; c < nch; c += nw) {
    int e0 = c << 6, len = min(64, E - e0);
    int ee = e0 + (lane < len ? lane : len - 1);
    int idxs = csrc[ee], idxd = cdst[ee];
    // lane-parallel gate: we = nodew[src] * exp(silu(bn(p+q)))
    float gt = (p[idxs] + q[idxd]) * gsc + gsh;
    gt = gt * frcp(1.f + fexp(-gt));
    float we = nodew[idxs] * fexp(gt);
    int dcur = __shfl(idxd, 0);
    float c0, c1;
    { unsigned vp = *(const unsigned*)(UVb + ((size_t)dcur << 8) + 128 + f0);
      c0 = bf2f(vp & 0xffffu) * sc0 + sh0; c1 = bf2f(vp >> 16) * sc1 + sh1; }
    float h0 = 0, h1 = 0, sw = 0;
    #define LDU(i) (*(const unsigned*)(UVb + ((size_t)__shfl(idxs, (i) < len ? (i) : len - 1) << 8) + f0))
    unsigned a0 = LDU(0), a1 = LDU(1), a2 = LDU(2), a3 = LDU(3);
    for (int bs = 0; bs < len; bs += 4) {
      unsigned b0 = LDU(bs + 4), b1 = LDU(bs + 5), b2 = LDU(bs + 6), b3 = LDU(bs + 7);
      #define PROCW(i, up) if ((i) < len) {                                          \
        int d = __shfl(idxd, (i));                                                   \
        float a = __shfl(we, (i));                                                   \
        if (d != dcur) {                                                             \
          atomicAdd(&h[((size_t)dcur << 7) + f0], h0);                               \
          atomicAdd(&h[((size_t)dcur << 7) + f1], h1);                               \
          if (lane == 0) atomicAdd(&sum_w[dcur], sw);                                \
          h0 = h1 = 0; sw = 0; dcur = d;                                             \
          unsigned vp = *(const unsigned*)(UVb + ((size_t)d << 8) + 128 + f0);       \
          c0 = bf2f(vp & 0xffffu) * sc0 + sh0; c1 = bf2f(vp >> 16) * sc1 + sh1;      \
        }                                                                            \
        float v0 = bf2f((up) & 0xffffu) * sc0 + c0;                                  \
        float v1 = bf2f((up) >> 16)     * sc1 + c1;                                  \
        v0 = v0 * frcp(1.f + fexp(-v0));                                             \
        v1 = v1 * frcp(1.f + fexp(-v1));                                             \
        h0 += a * v0; h1 += a * v1; sw += a; }
      PROCW(bs + 0, a0); PROCW(bs + 1, a1); PROCW(bs + 2, a2); PROCW(bs + 3, a3);
      a0 = b0; a1 = b1; a2 = b2; a3 = b3;
    }
    atomicAdd(&h[((size_t)dcur << 7) + f0], h0);
    atomicAdd(&h[((size_t)dcur << 7) + f1], h1);
    if (lane == 0) atomicAdd(&sum_w[dcur], sw);
    #undef PROCW
    #undef LDU
  }
}

// ---------------- reparameterize (bf16 muv=[mu|lv] packed [N,256]) + kld -----------------
__global__ void reparam_kernel(const unsigned short* __restrict__ muv,
                               const float* __restrict__ eps,
                               float* __restrict__ x, unsigned short* __restrict__ xb,
                               float* __restrict__ kacc, size_t total) {
  float part = 0;
  for (size_t i = (size_t)blockIdx.x * blockDim.x + threadIdx.x; i < total;
       i += (size_t)gridDim.x * blockDim.x) {
    size_t n = i >> 7; int f = (int)(i & 127);
    float m = bf2f(muv[(n << 8) + f]);
    float l = bf2f(muv[(n << 8) + 128 + f]);
    float el = fexp(l);
    float v = eps[i] * fexp(0.5f * l) + m;
    x[i] = v;
    xb[i] = f2bf(v);
    part += 1.f + l - m * m - el;
  }
  #pragma unroll
  for (int o = 32; o; o >>= 1) part += __shfl_down(part, o);
  __shared__ float la[4];
  int lane = threadIdx.x & 63, wid = threadIdx.x >> 6;
  if (lane == 0) la[wid] = part;
  __syncthreads();
  if (threadIdx.x == 0) atomicAdd(kacc, la[0] + la[1] + la[2] + la[3]);
}

// ---------------- pooling: sorted gid -> run-length segmented wave sum -------------------
__global__ void pool_kernel(const float* __restrict__ x, const int* __restrict__ gid,
                            float* __restrict__ pools, float* __restrict__ cnt, int N) {
  int lane = threadIdx.x & 63;
  int gw = (blockIdx.x * 256 + threadIdx.x) >> 6;
  int nw = (gridDim.x * 256) >> 6;
  int f0 = lane * 2, f1 = f0 + 1;
  const int CH = 64;
  int nch = (N + CH - 1) / CH;
  for (int c = gw; c < nch; c += nw) {
    int n0 = c * CH, n1 = min(N, n0 + CH);
    int gcur = gid[n0];
    float a0 = 0, a1 = 0, count = 0;
    for (int n = n0; n < n1; ++n) {
      int g = gid[n];
      if (g != gcur) {
        atomicAdd(&pools[((size_t)gcur << 7) + f0], a0);
        atomicAdd(&pools[((size_t)gcur << 7) + f1], a1);
        if (lane == 0) atomicAdd(&cnt[gcur], count);
        a0 = a1 = 0; count = 0; gcur = g;
      }
      float2 xv = *(const float2*)(x + ((size_t)n << 7) + f0);
      a0 += xv.x; a1 += xv.y; count += 1.f;
    }
    atomicAdd(&pools[((size_t)gcur << 7) + f0], a0);
    atomicAdd(&pools[((size_t)gcur << 7) + f1], a1);
    if (lane == 0) atomicAdd(&cnt[gcur], count);
  }
}

__global__ void finalize_kernel(const float* __restrict__ pools, const float* __restrict__ cnt,
                                const float* __restrict__ kacc, float* __restrict__ out,
                                int NG, float invN) {
  int i = blockIdx.x * blockDim.x + threadIdx.x;
  if (i < NG * 128) {
    float c = cnt[i >> 7];
    c = c > 1.f ? c : 1.f;
    out[i] = pools[i] / c;
  }
  if (i == 0) out[NG * 128] = -0.5f * kacc[0] * invN;
}

// =========================================================================================
extern "C" void kernel_launch(void* const* d_in, const int* in_sizes, int n_in,
                              void* d_out, int out_size, void* d_ws, size_t ws_size,
                              hipStream_t stream) {
  const float* atom    = (const float*)d_in[0];
  const float* nodew   = (const float*)d_in[1];
  const float* epsp    = (const float*)d_in[2];
  const int*   src     = (const int*)d_in[3];
  const int*   dst     = (const int*)d_in[4];
  const int*   gid     = (const int*)d_in[5];
  const float* W_embed = (const float*)d_in[6];
  const float* b_embed = (const float*)d_in[7];
  const float* g_embed = (const float*)d_in[8];
  const float* be_embed= (const float*)d_in[9];
  const float* Wf      = (const float*)d_in[10];
  const float* bfp     = (const float*)d_in[11];
  const float* gfp     = (const float*)d_in[12];
  const float* befp    = (const float*)d_in[13];
  const float* Wg      = (const float*)d_in[14];
  const float* bg      = (const float*)d_in[15];
  const float* gg      = (const float*)d_in[16];
  const float* beg     = (const float*)d_in[17];
  const float* gn      = (const float*)d_in[18];
  const float* ben     = (const float*)d_in[19];
  const float* W_mu    = (const float*)d_in[20];
  const float* b_mu    = (const float*)d_in[21];
  const float* W_var   = (const float*)d_in[22];
  const float* b_var   = (const float*)d_in[23];

  const int N   = in_sizes[1];
  const int E   = in_sizes[3];
  const int AIN = in_sizes[0] / N;
  const int NG  = (out_size - 1) / HID;

  char* w = (char*)d_ws;
  size_t off = 0;
  auto alloc = [&](size_t bytes) { size_t r = off; off = (off + bytes + 255) & ~(size_t)255; return r; };
  size_t o_x    = alloc((size_t)N*HID*4);
  size_t o_xb   = alloc((size_t)N*HID*2);
  size_t o_uvb  = alloc((size_t)N*256*2);
  size_t o_sw   = alloc((size_t)N*4);        // sum_w ...
  size_t o_h    = alloc((size_t)N*HID*4);    // ... h adjacent (single memset)
  size_t o_ab   = alloc((size_t)N*224*2);
  size_t o_p    = alloc((size_t)N*4);
  size_t o_q    = alloc((size_t)N*4);
  size_t o_csrc = alloc((size_t)E*4);
  size_t o_cdst = alloc((size_t)E*4);
  size_t o_cs   = alloc((size_t)(N+1)*4);
  size_t o_deg  = alloc((size_t)3*N*4);      // indeg | fill | outdeg
  size_t o_excl = alloc((size_t)N*4);
  size_t o_tot  = alloc(512*4);
  size_t o_bt   = alloc((size_t)256*128*2);
  size_t o_bias = alloc(256*4);
  // stats: [0:2) gate sum/nodesq; [2:34) gc_parts; [34:290) z; [290:546) node; [546:+4096) zc_parts
  size_t o_st   = alloc((546 + 32*128)*4);
  size_t o_kp   = alloc((size_t)(64 + NG*HID + NG)*4);

  float* x              = (float*)(w + o_x);
  unsigned short* xb    = (unsigned short*)(w + o_xb);
  unsigned short* UVb   = (unsigned short*)(w + o_uvb);
  float* sum_w          = (float*)(w + o_sw);
  float* h              = (float*)(w + o_h);
  unsigned short* atomb = (unsigned short*)(w + o_ab);
  float* p              = (float*)(w + o_p);
  float* q              = (float*)(w + o_q);
  int*   csrc           = (int*)(w + o_csrc);
  int*   cdst           = (int*)(w + o_cdst);
  int*   cstart         = (int*)(w + o_cs);
  int*   indeg          = (int*)(w + o_deg);
  int*   fill           = indeg + N;
  int*   outdeg         = indeg + 2*N;
  int*   excl           = (int*)(w + o_excl);
  int*   totals         = (int*)(w + o_tot);
  int*   tot_excl       = totals + 256;
  unsigned short* Bt    = (unsigned short*)(w + o_bt);
  float* bias           = (float*)(w + o_bias);
  float* stats          = (float*)(w + o_st);
  float* gstats         = stats;
  float* gc_parts       = stats + 2;
  float* zstats         = stats + 34;
  float* nstats         = stats + 290;
  float* zc_parts       = stats + 546;
  float* kacc           = (float*)(w + o_kp);
  float* pools          = kacc + 64;
  float* cnt            = pools + (size_t)NG*HID;

  const dim3 B(256);
  const int mblk = (N + 63) / 64;
  const int nb1  = (N + 255) / 256;
  const float invN = 1.f / (float)N;
  const float invE = 1.f / (float)E;
  const size_t totalNH = (size_t)N * HID;
  const size_t st_bytes = (546 + 32*128) * 4;
  const size_t swh_bytes = (o_h + (size_t)N*HID*4) - o_sw;

  // ---- zero accumulators ----
  hipMemsetAsync(w + o_st, 0, st_bytes, stream);
  hipMemsetAsync(w + o_kp, 0, (64 + (size_t)NG*HID + NG)*4, stream);
  hipMemsetAsync(w + o_deg, 0, (size_t)3*N*4, stream);

  // ---- CSR build (dst-sorted) + degrees ----
  hist_kernel<<<dim3(1024), B, 0, stream>>>(dst, indeg, E);
  hist_kernel<<<dim3(1024), B, 0, stream>>>(src, outdeg, E);
  scan_block_kernel<<<dim3(nb1), B, 0, stream>>>(indeg, N, excl, totals);
  scan_block_kernel<<<dim3(1), B, 0, stream>>>(totals, nb1, tot_excl, nullptr);
  scan_add_kernel<<<dim3(nb1), B, 0, stream>>>(excl, tot_excl, indeg, cstart, N);
  scatter_kernel<<<dim3(1024), B, 0, stream>>>(src, dst, cstart, fill, csrc, E);
  fill_cdst_kernel<<<dim3(256), B, 0, stream>>>(cstart, cdst, N);

  // ---- atom embedding ----
  cast_atom_kernel<<<dim3(N), B, 0, stream>>>(atom, atomb, N, AIN);
  prep_we_kernel<<<dim3(112), B, 0, stream>>>(W_embed, Bt, AIN);
  gemm_bf16_kernel<7, 8, false, false><<<dim3(mblk), B, 0, stream>>>(
      atomb, Bt, b_embed, h, N, nullptr, nullptr, nullptr);
  colstats_kernel<false><<<dim3(512), B, 0, stream>>>(h, nullptr, N, nstats);
  bn_act_kernel<true,false,false><<<dim3(2048), B, 0, stream>>>(
      h, nullptr, nstats, g_embed, be_embed, x, invN, x, xb, totalNH);

  for (int l = 0; l < LAYERS; ++l) {
    if (l == 1) {
      prep_mv_kernel<<<dim3(128), B, 0, stream>>>(W_mu, W_var, b_mu, b_var, Bt, bias);
      gemm_bf16_kernel<4, 16, true, false><<<dim3(mblk), B, 0, stream>>>(
          xb, Bt, bias, UVb, N, nullptr, nullptr, nullptr);
      reparam_kernel<<<dim3(2048), B, 0, stream>>>(UVb, epsp, x, xb, kacc, totalNH);
    }
    prep_wg_kernel<<<dim3(128), B, 0, stream>>>(Wg + (size_t)l*4*256*32, bg + l*128, Bt, bias);
    hipMemsetAsync(w + o_st, 0, st_bytes, stream);
    hipMemsetAsync(w + o_sw, 0, swh_bytes, stream);   // sum_w + h
    gemm_bf16_kernel<4, 16, true, true><<<dim3(mblk), B, 0, stream>>>(
        xb, Bt, bias, UVb, N, indeg, outdeg, zstats);
    pq_kernel<<<dim3(512), B, 0, stream>>>(xb, Wf + l*256, bfp + l, indeg, outdeg,
                                           p, q, gstats, N);
    xwalk_kernel<<<dim3(2048), B, 0, stream>>>(UVb, csrc, cdst, p, q, zc_parts, gc_parts, E);
    walk2_kernel<<<dim3(2048), B, 0, stream>>>(UVb, csrc, cdst, p, q, nodew,
                                               gstats, gc_parts, gfp + l, befp + l,
                                               zstats, zc_parts, gg + l*128, beg + l*128,
                                               h, sum_w, E, invE);
    colstats_kernel<true><<<dim3(512), B, 0, stream>>>(h, sum_w, N, nstats);
    bn_act_kernel<false,true,true><<<dim3(2048), B, 0, stream>>>(
        h, sum_w, nstats, gn + l*128, ben + l*128, x, invN, x, xb, totalNH);
  }

  // ---- pooling + output ----
  pool_kernel<<<dim3(256), B, 0, stream>>>(x, gid, pools, cnt, N);
  finalize_kernel<<<dim3((NG*HID + 255)/256), B, 0, stream>>>(pools, cnt, kacc,
                                                              (float*)d_out, NG, invN);
}